// Round 12
// baseline (628.826 us; speedup 1.0000x reference)
//
#include <hip/hip_runtime.h>
#include <math.h>

#define HW 65536
#define NC 10
#define NT 12
#define LAMBDA_F 0.05f
#define PI_F 3.14159265358979323846f
// XOR-swizzle for wave-private LDS fft scratch
#define SWZ(i) ((i) ^ ((i) >> 4))
// part buffer rows (1024 floats each)
#define ROW_RS(it)  (it)            // rs_it partials: rows 0..9 (768 entries)
#define ROW_RMR(it) (16 + (it))     // rMr_it partials: rows 16..25 (640 entries)
#define NPART_ROWS 26

__device__ __forceinline__ float2 cadd(float2 a, float2 b){ return make_float2(a.x+b.x, a.y+b.y); }
__device__ __forceinline__ float2 csub(float2 a, float2 b){ return make_float2(a.x-b.x, a.y-b.y); }
__device__ __forceinline__ float2 cmul(float2 a, float2 b){ return make_float2(a.x*b.x-a.y*b.y, a.x*b.y+a.y*b.x); }
// conj(a)*b
__device__ __forceinline__ float2 cmulj(float2 a, float2 b){ return make_float2(a.x*b.x+a.y*b.y, a.x*b.y-a.y*b.x); }
__device__ __forceinline__ float2 cscale(float2 a, float s){ return make_float2(a.x*s, a.y*s); }

template<int SIGN>
__device__ __forceinline__ void radix4_nt(float2& a0, float2& a1, float2& a2, float2& a3){
  float2 t0=cadd(a0,a2), t1=csub(a0,a2), t2=cadd(a1,a3), t3=csub(a1,a3);
  float2 t3r;
  if constexpr (SIGN < 0) t3r = make_float2(t3.y, -t3.x); else t3r = make_float2(-t3.y, t3.x);
  a0=cadd(t0,t2); a1=cadd(t1,t3r); a2=csub(t0,t2); a3=csub(t1,t3r);
}

template<int SIGN>
__device__ __forceinline__ void radix4_tw(float2& a0, float2& a1, float2& a2, float2& a3, float2 w){
  if constexpr (SIGN > 0) w.y = -w.y;
  float2 w2 = cmul(w, w);
  float2 w3 = cmul(w, w2);
  a1 = cmul(a1, w); a2 = cmul(a2, w2); a3 = cmul(a3, w3);
  radix4_nt<SIGN>(a0, a1, a2, a3);
}

__device__ __forceinline__ float2 twf(int e){
  float s, c;
  __sincosf(-2.0f*PI_F*(float)e*(1.0f/256.0f), &s, &c);
  return make_float2(c, s);
}

// Single 256-pt Stockham radix-4 FFT, wave-private scratch b.
template<int SIGN>
__device__ __forceinline__ void fft256(float2* b, int j,
                                       float2 wA, float2 wB, float2 wC,
                                       float2& x0, float2& x1, float2& x2, float2& x3){
  radix4_nt<SIGN>(x0,x1,x2,x3);
  b[SWZ(4*j)]=x0; b[SWZ(4*j+1)]=x1; b[SWZ(4*j+2)]=x2; b[SWZ(4*j+3)]=x3;
  x0=b[SWZ(j)]; x1=b[SWZ(j+64)]; x2=b[SWZ(j+128)]; x3=b[SWZ(j+192)];
  radix4_tw<SIGN>(x0,x1,x2,x3, wA);
  { int i=((j>>2)<<4)+(j&3); b[SWZ(i)]=x0; b[SWZ(i+4)]=x1; b[SWZ(i+8)]=x2; b[SWZ(i+12)]=x3; }
  x0=b[SWZ(j)]; x1=b[SWZ(j+64)]; x2=b[SWZ(j+128)]; x3=b[SWZ(j+192)];
  radix4_tw<SIGN>(x0,x1,x2,x3, wB);
  { int i=((j>>4)<<6)+(j&15); b[SWZ(i)]=x0; b[SWZ(i+16)]=x1; b[SWZ(i+32)]=x2; b[SWZ(i+48)]=x3; }
  x0=b[SWZ(j)]; x1=b[SWZ(j+64)]; x2=b[SWZ(j+128)]; x3=b[SWZ(j+192)];
  radix4_tw<SIGN>(x0,x1,x2,x3, wC);
}

// Two independent FFTs, stage-interleaved (r8-r11, verified).
template<int SIGN>
__device__ __forceinline__ void fft256x2(float2* bA, float2* bB, int j,
    float2 wA, float2 wB, float2 wC,
    float2& a0, float2& a1, float2& a2, float2& a3,
    float2& b0, float2& b1, float2& b2, float2& b3){
  radix4_nt<SIGN>(a0,a1,a2,a3); radix4_nt<SIGN>(b0,b1,b2,b3);
  bA[SWZ(4*j)]=a0; bA[SWZ(4*j+1)]=a1; bA[SWZ(4*j+2)]=a2; bA[SWZ(4*j+3)]=a3;
  bB[SWZ(4*j)]=b0; bB[SWZ(4*j+1)]=b1; bB[SWZ(4*j+2)]=b2; bB[SWZ(4*j+3)]=b3;
  a0=bA[SWZ(j)]; a1=bA[SWZ(j+64)]; a2=bA[SWZ(j+128)]; a3=bA[SWZ(j+192)];
  b0=bB[SWZ(j)]; b1=bB[SWZ(j+64)]; b2=bB[SWZ(j+128)]; b3=bB[SWZ(j+192)];
  radix4_tw<SIGN>(a0,a1,a2,a3, wA); radix4_tw<SIGN>(b0,b1,b2,b3, wA);
  { int i=((j>>2)<<4)+(j&3);
    bA[SWZ(i)]=a0; bA[SWZ(i+4)]=a1; bA[SWZ(i+8)]=a2; bA[SWZ(i+12)]=a3;
    bB[SWZ(i)]=b0; bB[SWZ(i+4)]=b1; bB[SWZ(i+8)]=b2; bB[SWZ(i+12)]=b3; }
  a0=bA[SWZ(j)]; a1=bA[SWZ(j+64)]; a2=bA[SWZ(j+128)]; a3=bA[SWZ(j+192)];
  b0=bB[SWZ(j)]; b1=bB[SWZ(j+64)]; b2=bB[SWZ(j+128)]; b3=bB[SWZ(j+192)];
  radix4_tw<SIGN>(a0,a1,a2,a3, wB); radix4_tw<SIGN>(b0,b1,b2,b3, wB);
  { int i=((j>>4)<<6)+(j&15);
    bA[SWZ(i)]=a0; bA[SWZ(i+16)]=a1; bA[SWZ(i+32)]=a2; bA[SWZ(i+48)]=a3;
    bB[SWZ(i)]=b0; bB[SWZ(i+16)]=b1; bB[SWZ(i+32)]=b2; bB[SWZ(i+48)]=b3; }
  a0=bA[SWZ(j)]; a1=bA[SWZ(j+64)]; a2=bA[SWZ(j+128)]; a3=bA[SWZ(j+192)];
  b0=bB[SWZ(j)]; b1=bB[SWZ(j+64)]; b2=bB[SWZ(j+128)]; b3=bB[SWZ(j+192)];
  radix4_tw<SIGN>(a0,a1,a2,a3, wC); radix4_tw<SIGN>(b0,b1,b2,b3, wC);
}

// Exact-CG scalar chain (Hermitian M -> all scalars real). Verified r10/r11.
__device__ __forceinline__ void cg_chain3(const float* __restrict__ scal, int n,
                                          float rs_f, float rmr_f,
                                          float& alpha, float& beta){
  float mp = 0.f, P2 = 0.f, rs_prev = 1.f;
  alpha = 0.f; beta = 0.f;
  for (int k = 0; k < n; k++){
    float rsk  = (k == n-1) ? rs_f  : scal[k];
    float rmrk = (k == n-1) ? rmr_f : scal[32+k];
    if (k == 0){ beta = 0.f; mp = rmrk; P2 = rsk; }
    else {
      beta = rsk / rs_prev;
      mp = rmrk - 2.f*beta*rsk/alpha + beta*beta*mp;
      P2 = rsk + beta*beta*P2;
    }
    float pap = mp + LAMBDA_F*P2;
    alpha = rsk / pap;
    rs_prev = rsk;
  }
}

// W-combine for one output plane s (wave-uniform s -> no divergence)
__device__ __forceinline__ float2 w_combine(const float* __restrict__ W9, int wi, int s,
                                            float2 v0, float2 v1, float2 v2){
  if (s == 0){
    float d0 = W9[wi];
    float2 o01 = make_float2(W9[wi+3*HW], W9[wi+4*HW]);
    float2 o02 = make_float2(W9[wi+5*HW], W9[wi+6*HW]);
    return cadd(cadd(cscale(v0,d0), cmul(o01,v1)), cmul(o02,v2));
  } else if (s == 1){
    float d1 = W9[wi+HW];
    float2 o01 = make_float2(W9[wi+3*HW], W9[wi+4*HW]);
    float2 o12 = make_float2(W9[wi+7*HW], W9[wi+8*HW]);
    return cadd(cadd(cmulj(o01,v0), cscale(v1,d1)), cmul(o12,v2));
  } else {
    float d2 = W9[wi+2*HW];
    float2 o02 = make_float2(W9[wi+5*HW], W9[wi+6*HW]);
    float2 o12 = make_float2(W9[wi+7*HW], W9[wi+8*HW]);
    return cadd(cadd(cmulj(o02,v0), cmulj(o12,v1)), cscale(v2,d2));
  }
}

// ---------- W9 precompute + zero scal/part (small, 256 blocks)
__global__ __launch_bounds__(256) void k_W9(const float* __restrict__ mask,
                                            const float2* __restrict__ Lt,
                                            float* __restrict__ W9,
                                            float* __restrict__ scal,
                                            float* __restrict__ part){
  int tid = threadIdx.x, u = blockIdx.x;
  if (u == 0){
    if (tid < 128) scal[tid] = 0.0f;
    for (int i = tid; i < NPART_ROWS*1024; i += 256) part[i] = 0.0f;
  }
  int kx = u, ky = tid;
  int mx = (kx + 128) & 255, my = (ky + 128) & 255;
  float d0=0.f,d1=0.f,d2=0.f;
  float2 o01=make_float2(0,0), o02=make_float2(0,0), o12=make_float2(0,0);
  for (int t = 0; t < NT; t++){
    float m = mask[t*HW + my*256 + mx];
    float2 l0 = Lt[t*3+0], l1 = Lt[t*3+1], l2 = Lt[t*3+2];
    d0 += m*(l0.x*l0.x + l0.y*l0.y);
    d1 += m*(l1.x*l1.x + l1.y*l1.y);
    d2 += m*(l2.x*l2.x + l2.y*l2.y);
    o01 = cadd(o01, cscale(cmulj(l0,l1), m));
    o02 = cadd(o02, cscale(cmulj(l0,l2), m));
    o12 = cadd(o12, cscale(cmulj(l1,l2), m));
  }
  const float nrm = 1.0f/65536.0f;
  int idx = kx*256 + ky;
  W9[idx]      = d0*nrm;  W9[idx+HW]   = d1*nrm;  W9[idx+2*HW] = d2*nrm;
  W9[idx+3*HW] = o01.x*nrm; W9[idx+4*HW] = o01.y*nrm;
  W9[idx+5*HW] = o02.x*nrm; W9[idx+6*HW] = o02.y*nrm;
  W9[idx+7*HW] = o12.x*nrm; W9[idx+8*HW] = o12.y*nrm;
}

// ---------- FUSED setup row pass: g_{c,s} = D sum_t conj(L_ts) y[t,c] computed
// in registers (3 s-planes share the y row reads), row-IFFT (-1), transposed
// write -> bufR [pl][kx][y]. grid (32 row-tiles, 10 c), 512 thr = 8 waves x 1 row.
__global__ __launch_bounds__(512) void k_rows_g(const float2* __restrict__ y,
                                                const float2* __restrict__ Lt,
                                                float2* __restrict__ dst){
  __shared__ float2 T[8][3][256];   // 48 KB
  int tid = threadIdx.x, g = tid >> 6, j = tid & 63;
  float2 wA = twf((j&3)<<4), wB = twf((j&15)<<2), wC = twf(j);
  int ri = blockIdx.x, c = blockIdx.y;
  int row = ri*8 + g;
  float2 acc[3][4];
  #pragma unroll
  for (int s = 0; s < 3; s++)
    #pragma unroll
    for (int q = 0; q < 4; q++) acc[s][q] = make_float2(0,0);
  for (int t = 0; t < NT; t++){
    const float2* yr = y + ((size_t)(t*NC + c))*HW + row*256;
    float2 l0 = Lt[t*3+0], l1 = Lt[t*3+1], l2 = Lt[t*3+2];
    #pragma unroll
    for (int q = 0; q < 4; q++){
      float2 yv = yr[j + 64*q];
      acc[0][q] = cadd(acc[0][q], cmulj(l0, yv));
      acc[1][q] = cadd(acc[1][q], cmulj(l1, yv));
      acc[2][q] = cadd(acc[2][q], cmulj(l2, yv));
    }
  }
  #pragma unroll
  for (int s = 0; s < 3; s++){
    float2 x0, x1, x2, x3;
    {
      float sg0 = ((j + row) & 1) ? -1.0f : 1.0f;
      x0 = cscale(acc[s][0], sg0);
      x1 = cscale(acc[s][1], sg0);
      x2 = cscale(acc[s][2], sg0);
      x3 = cscale(acc[s][3], sg0);
    }
    fft256<-1>(T[g][s], j, wA,wB,wC, x0,x1,x2,x3);
    T[g][s][j]=x0; T[g][s][j+64]=x1; T[g][s][j+128]=x2; T[g][s][j+192]=x3;
  }
  __syncthreads();
  int yo2 = (tid&3)*2, kxo = tid>>2;
  #pragma unroll
  for (int s = 0; s < 3; s++){
    float2* dT = dst + ((size_t)(c*3+s))*HW;
    #pragma unroll
    for (int kb = 0; kb < 2; kb++){
      int kx = kb*128 + kxo;
      float2 a = T[yo2][s][kx], b = T[yo2+1][s][kx];
      *(float4*)(dT + (size_t)kx*256 + ri*8 + yo2) = make_float4(a.x,a.y,b.x,b.y);
    }
  }
}

// ---------- setup col IFFT (-1): bufR [pl][kx][y] contiguous -> bufB row-major
__global__ __launch_bounds__(512) void k_cols_plain(const float2* __restrict__ src,
                                                    float2* __restrict__ dst){
  __shared__ float2 tile[8][256];
  int tid = threadIdx.x, g = tid >> 6, j = tid & 63;
  float2 wA = twf((j&3)<<4), wB = twf((j&15)<<2), wC = twf(j);
  int pl = blockIdx.y, kg = blockIdx.x;
  int kx = kg*8 + g;
  const float2* col = src + (size_t)pl*HW + (size_t)kx*256;
  float2 x0=col[j], x1=col[j+64], x2=col[j+128], x3=col[j+192];
  fft256<-1>(tile[g], j, wA,wB,wC, x0,x1,x2,x3);
  tile[g][j]=x0; tile[g][j+64]=x1; tile[g][j+128]=x2; tile[g][j+192]=x3;
  __syncthreads();
  float2* d = dst + (size_t)pl*HW;
  int kxo2 = (tid&3)*2, yy = tid>>2;
  #pragma unroll
  for (int yb = 0; yb < 2; yb++){
    int yc = yb*128 + yy;
    float2 a = tile[kxo2][yc], b = tile[kxo2+1][yc];
    *(float4*)(d + (size_t)yc*256 + kg*8 + kxo2) = make_float4(a.x,a.y,b.x,b.y);
  }
}

// ---------- BIG-ROW kernel. grid (256 rows, 3 s), 640 thr = 10 waves (wave = coil).
// MODE 0: b = D*sum_c conj(S_c)*A + lambda*mo ; r0=b ; z=0 ; rs0 partial ;
//         then FFT S_c*r0 -> bufR.
// MODE 1 (iter>=1): bufB holds K2(S r_{it-1}) -> row-IFFT + combine = Mr_{it-1};
//   chain -> alpha,beta; p/Mp/z/r updates; rs_it partial; FFT S_c*r_new -> bufR.
template<int MODE>
__global__ __launch_bounds__(640) void k_bigrow(const float2* __restrict__ bufB,
                                                const float2* __restrict__ sens,
                                                const float2* __restrict__ mo,
                                                float2* __restrict__ rbuf,
                                                float2* __restrict__ pbuf,
                                                float2* __restrict__ Mpb,
                                                float2* __restrict__ zbuf,
                                                float2* __restrict__ bufR,
                                                float* __restrict__ scal,
                                                float* __restrict__ part, int iter){
  __shared__ float2 scratch[10][256];
  __shared__ float2 rnew_s[256];
  __shared__ float redv[10];
  __shared__ float sA[2];
  int tid = threadIdx.x, w = tid >> 6, j = tid & 63;
  float2 wA = twf((j&3)<<4), wB = twf((j&15)<<2), wC = twf(j);
  int row = blockIdx.x, s = blockIdx.y;

  if constexpr (MODE == 1){
    // --- reduce fresh scalar partials: rs_{it-1} (768) and rMr_{it-1} (640)
    int rowsel[2] = { ROW_RS(iter-1), ROW_RMR(iter-1) };
    #pragma unroll
    for (int q = 0; q < 2; q++){
      const float* P = part + rowsel[q]*1024;
      float v = P[tid] + ((tid < 384) ? P[tid+640] : 0.f);
      for (int off = 32; off; off >>= 1) v += __shfl_down(v, off);
      if (j == 0) redv[w] = v;
      __syncthreads();
      if (tid == 0){
        float t = 0.f;
        #pragma unroll
        for (int k = 0; k < 10; k++) t += redv[k];
        sA[q] = t;
      }
      __syncthreads();
    }
    float alpha, beta;
    cg_chain3(scal, iter, sA[0], sA[1], alpha, beta);
    if (blockIdx.x == 0 && blockIdx.y == 0 && tid == 0){
      scal[iter-1]    = sA[0];
      scal[32+iter-1] = sA[1];
    }

    // --- phase 1: row IFFT of bufB per coil + conj(S)
    {
      int c = w;
      const float2* src = bufB + ((size_t)(c*3+s))*HW + row*256;
      float2 x0=src[j], x1=src[j+64], x2=src[j+128], x3=src[j+192];
      fft256<-1>(scratch[c], j, wA,wB,wC, x0,x1,x2,x3);
      const float2* Sc = sens + (size_t)c*HW + row*256;
      scratch[c][j]     = cmulj(Sc[j],     x0);
      scratch[c][j+64]  = cmulj(Sc[j+64],  x1);
      scratch[c][j+128] = cmulj(Sc[j+128], x2);
      scratch[c][j+192] = cmulj(Sc[j+192], x3);
    }
    __syncthreads();
    // --- phase 2: combine -> Mr; CG updates (threads 0..255)
    if (tid < 256){
      int k = tid;
      float2 Mr = make_float2(0,0);
      #pragma unroll
      for (int c = 0; c < NC; c++) Mr = cadd(Mr, scratch[c][k]);
      size_t ob = (size_t)s*HW + row*256 + k;
      float2 rold = rbuf[ob];
      float2 pcur, Mpc;
      if (iter == 1){ pcur = rold; Mpc = Mr; }
      else {
        pcur = cadd(rold, cscale(pbuf[ob], beta));
        Mpc  = cadd(Mr,   cscale(Mpb[ob],  beta));
      }
      Mpb[ob]  = Mpc;
      pbuf[ob] = pcur;
      float2 Ap = cadd(Mpc, cscale(pcur, LAMBDA_F));
      float2 zo = zbuf[ob];
      zbuf[ob] = make_float2(zo.x + alpha*pcur.x, zo.y + alpha*pcur.y);
      float2 rnew = make_float2(rold.x - alpha*Ap.x, rold.y - alpha*Ap.y);
      rbuf[ob] = rnew;
      rnew_s[k] = rnew;
      float pv2 = rnew.x*rnew.x + rnew.y*rnew.y;
      for (int off = 32; off; off >>= 1) pv2 += __shfl_down(pv2, off);
      if (j == 0) redv[w] = pv2;   // w in 0..3 here
    }
    __syncthreads();
    if (tid == 0)
      part[ROW_RS(iter)*1024 + s*256 + row] = redv[0]+redv[1]+redv[2]+redv[3];
  } else {
    // MODE 0: fused compute_b. bufB = A (image planes).
    if (tid < 256){
      int k = tid;
      float sg = ((k + row) & 1) ? -1.0f : 1.0f;
      float2 accv = make_float2(0,0);
      #pragma unroll
      for (int c = 0; c < NC; c++)
        accv = cadd(accv, cmulj(sens[(size_t)c*HW + row*256 + k],
                                bufB[((size_t)(c*3+s))*HW + row*256 + k]));
      size_t ob = (size_t)s*HW + row*256 + k;
      float2 b = cadd(cscale(accv, sg), cscale(mo[ob], LAMBDA_F));
      rbuf[ob] = b; zbuf[ob] = make_float2(0,0);
      rnew_s[k] = b;
      float pv2 = b.x*b.x + b.y*b.y;
      for (int off = 32; off; off >>= 1) pv2 += __shfl_down(pv2, off);
      if (j == 0) redv[w] = pv2;
    }
    __syncthreads();
    if (tid == 0)
      part[ROW_RS(0)*1024 + s*256 + row] = redv[0]+redv[1]+redv[2]+redv[3];
  }

  // --- phase 3: FFT S_c * r_new -> bufR row-major (coalesced)
  {
    int c = w;
    const float2* Sc = sens + (size_t)c*HW + row*256;
    float2 x0 = cmul(Sc[j],     rnew_s[j]);
    float2 x1 = cmul(Sc[j+64],  rnew_s[j+64]);
    float2 x2 = cmul(Sc[j+128], rnew_s[j+128]);
    float2 x3 = cmul(Sc[j+192], rnew_s[j+192]);
    fft256<1>(scratch[c], j, wA,wB,wC, x0,x1,x2,x3);
    float2* d = bufR + ((size_t)(c*3+s))*HW + row*256;
    d[j]=x0; d[j+64]=x1; d[j+128]=x2; d[j+192]=x3;
  }
}

// ---------- COL kernel: 4 columns per block, 384 thr = 6 waves (2 cols each via
// fft256x2). grid (64 kx-groups, 10 c) = 640 blocks -> 5 blocks/CU, balanced
// (r9-verified gather/scatter indexing; r10-verified no-Kp math + rMr Parseval).
__global__ __launch_bounds__(384) void k_colW(const float2* __restrict__ bufR,
                                              float2* __restrict__ bufB,
                                              const float* __restrict__ W9,
                                              float* __restrict__ part, int iter){
  __shared__ float2 T[12][256];   // 24 KB: [s*4 + local_col][row]
  __shared__ float redp[6];
  int tid = threadIdx.x, w = tid >> 6, j = tid & 63;
  float2 wA = twf((j&3)<<4), wB = twf((j&15)<<2), wC = twf(j);
  int kg = blockIdx.x, c = blockIdx.y;
  int s = w >> 1, kxp = w & 1;
  int kxl0 = kxp*2, kxl1 = kxl0 + 1;
  int kx0 = kg*4 + kxl0, kx1 = kg*4 + kxl1;

  // --- gather: 3 planes x 4 cols x 256 rows = 1536 float4, 4 per thread
  #pragma unroll
  for (int f = 0; f < 4; f++){
    int idx = f*384 + tid;            // 0..1535
    int sp = idx >> 9, rem = idx & 511, rrow = rem >> 1, cp = rem & 1;
    const float4* s4 = (const float4*)(bufR + ((size_t)(c*3+sp))*HW);
    float4 v = s4[(size_t)rrow*128 + kg*2 + cp];
    T[sp*4 + cp*2 + 0][rrow] = make_float2(v.x, v.y);
    T[sp*4 + cp*2 + 1][rrow] = make_float2(v.z, v.w);
  }
  __syncthreads();

  // --- col FFT(+1), 2 columns per wave, in place
  {
    float2 a0=T[s*4+kxl0][j], a1=T[s*4+kxl0][j+64], a2=T[s*4+kxl0][j+128], a3=T[s*4+kxl0][j+192];
    float2 b0=T[s*4+kxl1][j], b1=T[s*4+kxl1][j+64], b2=T[s*4+kxl1][j+128], b3=T[s*4+kxl1][j+192];
    fft256x2<1>(T[s*4+kxl0], T[s*4+kxl1], j, wA,wB,wC, a0,a1,a2,a3, b0,b1,b2,b3);
    T[s*4+kxl0][j]=a0; T[s*4+kxl0][j+64]=a1; T[s*4+kxl0][j+128]=a2; T[s*4+kxl0][j+192]=a3;
    T[s*4+kxl1][j]=b0; T[s*4+kxl1][j+64]=b1; T[s*4+kxl1][j+128]=b2; T[s*4+kxl1][j+192]=b3;
  }
  __syncthreads();

  // --- U = W V + Parseval rMr partial (Re only; exact-math Im sums to 0)
  float2 UA[4], UB[4];
  float pr = 0.f;
  #pragma unroll
  for (int q = 0; q < 4; q++){
    int k = j + 64*q;
    {
      float2 v0 = T[0+kxl0][k], v1 = T[4+kxl0][k], v2 = T[8+kxl0][k];
      float2 U = w_combine(W9, kx0*256 + k, s, v0, v1, v2);
      UA[q] = U;
      float2 vs = (s==0) ? v0 : ((s==1) ? v1 : v2);
      pr += vs.x*U.x + vs.y*U.y;
    }
    {
      float2 v0 = T[0+kxl1][k], v1 = T[4+kxl1][k], v2 = T[8+kxl1][k];
      float2 U = w_combine(W9, kx1*256 + k, s, v0, v1, v2);
      UB[q] = U;
      float2 vs = (s==0) ? v0 : ((s==1) ? v1 : v2);
      pr += vs.x*U.x + vs.y*U.y;
    }
  }
  __syncthreads();   // all V reads done before T reused as IFFT scratch

  // --- col IFFT(-1)
  {
    float2 a0=UA[0], a1=UA[1], a2=UA[2], a3=UA[3];
    float2 b0=UB[0], b1=UB[1], b2=UB[2], b3=UB[3];
    fft256x2<-1>(T[s*4+kxl0], T[s*4+kxl1], j, wA,wB,wC, a0,a1,a2,a3, b0,b1,b2,b3);
    T[s*4+kxl0][j]=a0; T[s*4+kxl0][j+64]=a1; T[s*4+kxl0][j+128]=a2; T[s*4+kxl0][j+192]=a3;
    T[s*4+kxl1][j]=b0; T[s*4+kxl1][j+64]=b1; T[s*4+kxl1][j+128]=b2; T[s*4+kxl1][j+192]=b3;
  }
  // --- reduce rMr partial
  for (int off = 32; off; off >>= 1) pr += __shfl_down(pr, off);
  if (j == 0) redp[w] = pr;
  __syncthreads();
  if (tid == 0){
    float t = 0.f;
    #pragma unroll
    for (int k = 0; k < 6; k++) t += redp[k];
    part[ROW_RMR(iter)*1024 + c*64 + kg] = t;
  }
  // --- scatter to bufB row-major (mirror of gather)
  #pragma unroll
  for (int yb = 0; yb < 4; yb++){
    int flat = yb*384 + tid;
    int s_out = flat >> 9;
    int rem = flat & 511;
    int kxo2 = (rem >> 8) << 1;
    int yc = rem & 255;
    float2 a = T[s_out*4+kxo2][yc], b = T[s_out*4+kxo2+1][yc];
    float2* d = bufB + ((size_t)(c*3+s_out))*HW;
    *(float4*)(d + (size_t)yc*256 + kg*4 + kxo2) = make_float4(a.x,a.y,b.x,b.y);
  }
}

// ---------- final: reduce rs_9, rMr_9 ; p9 = r9 + beta9*p8 ; z += alpha9*p9
__global__ __launch_bounds__(256) void k_final(float2* __restrict__ z,
                                               const float2* __restrict__ rbuf,
                                               const float2* __restrict__ pbuf,
                                               const float* __restrict__ scal,
                                               const float* __restrict__ part){
  __shared__ float redv[4];
  __shared__ float sA[2];
  int tid = threadIdx.x, w = tid >> 6, j = tid & 63;
  int rowsel[2] = { ROW_RS(9), ROW_RMR(9) };
  #pragma unroll
  for (int q = 0; q < 2; q++){
    const float* P = part + rowsel[q]*1024;
    float v = P[tid] + P[tid+256] + P[tid+512] + P[tid+768];
    for (int off = 32; off; off >>= 1) v += __shfl_down(v, off);
    if (j == 0) redv[w] = v;
    __syncthreads();
    if (tid == 0) sA[q] = redv[0]+redv[1]+redv[2]+redv[3];
    __syncthreads();
  }
  float alpha, beta;
  cg_chain3(scal, 10, sA[0], sA[1], alpha, beta);
  int idx = blockIdx.x*256 + tid;
  float2 r9 = rbuf[idx], p8 = pbuf[idx];
  float2 p9 = cadd(r9, cscale(p8, beta));
  float2 zo = z[idx];
  z[idx] = make_float2(zo.x + alpha*p9.x, zo.y + alpha*p9.y);
}

extern "C" void kernel_launch(void* const* d_in, const int* in_sizes, int n_in,
                              void* d_out, int out_size, void* d_ws, size_t ws_size,
                              hipStream_t stream){
  const float2* y    = (const float2*)d_in[0];
  const float2* mo   = (const float2*)d_in[1];
  const float2* sens = (const float2*)d_in[2];
  const float2* Lt   = (const float2*)d_in[3];
  const float*  mask = (const float*)d_in[4];

  float* w = (float*)d_ws;
  float*  scal = w;                                   // 128 floats (rs chain + rMr chain)
  float*  part = w + 128;                             // 26*1024 floats
  float*  W9   = part + NPART_ROWS*1024;              // 9*HW floats
  float2* bufB = (float2*)(W9 + 9*HW);                // 30 planes row-major
  float2* bufR = bufB + (size_t)30*HW;                // 30 planes row-major k-rows / setup transpose
  float2* rb   = bufR + (size_t)30*HW;                // 3 planes residual
  float2* pb   = rb + (size_t)3*HW;                   // 3 planes direction
  float2* Mpb  = pb + (size_t)3*HW;                   // 3 planes M*p recurrence
  float2* z    = (float2*)d_out;

  // setup (fused): W9 ; g+rowIFFT->bufR_T ; colIFFT->bufB(A) ; b+r0+FFT rows
  k_W9<<<256, 256, 0, stream>>>(mask, Lt, W9, scal, part);
  k_rows_g<<<dim3(32, 10), 512, 0, stream>>>(y, Lt, bufR);
  k_cols_plain<<<dim3(32, 30), 512, 0, stream>>>(bufR, bufB);
  k_bigrow<0><<<dim3(256, 3), 640, 0, stream>>>(bufB, sens, mo, rb, pb, Mpb, z, bufR, scal, part, 0);

  // CG loop: 2 kernels per iteration
  for (int it = 0; it < 10; it++){
    if (it > 0)
      k_bigrow<1><<<dim3(256, 3), 640, 0, stream>>>(bufB, sens, mo, rb, pb, Mpb, z, bufR, scal, part, it);
    k_colW<<<dim3(64, 10), 384, 0, stream>>>(bufR, bufB, W9, part, it);
  }
  k_final<<<768, 256, 0, stream>>>(z, rb, pb, scal, part);
}

// Round 13
// 495.008 us; speedup vs baseline: 1.2703x; 1.2703x over previous
//
#include <hip/hip_runtime.h>
#include <math.h>

#define HW 65536
#define NC 10
#define NT 12
#define LAMBDA_F 0.05f
#define PI_F 3.14159265358979323846f
// XOR-swizzle for wave-private LDS fft scratch
#define SWZ(i) ((i) ^ ((i) >> 4))
// part buffer rows (1024 floats each)
#define ROW_RS(it)  (it)            // rs_it partials: rows 0..9 (768 entries)
#define ROW_RMR(it) (16 + (it))     // rMr_it partials: rows 16..25 (640 entries)
#define NPART_ROWS 26

__device__ __forceinline__ float2 cadd(float2 a, float2 b){ return make_float2(a.x+b.x, a.y+b.y); }
__device__ __forceinline__ float2 csub(float2 a, float2 b){ return make_float2(a.x-b.x, a.y-b.y); }
__device__ __forceinline__ float2 cmul(float2 a, float2 b){ return make_float2(a.x*b.x-a.y*b.y, a.x*b.y+a.y*b.x); }
// conj(a)*b
__device__ __forceinline__ float2 cmulj(float2 a, float2 b){ return make_float2(a.x*b.x+a.y*b.y, a.x*b.y-a.y*b.x); }
__device__ __forceinline__ float2 cscale(float2 a, float s){ return make_float2(a.x*s, a.y*s); }

template<int SIGN>
__device__ __forceinline__ void radix4_nt(float2& a0, float2& a1, float2& a2, float2& a3){
  float2 t0=cadd(a0,a2), t1=csub(a0,a2), t2=cadd(a1,a3), t3=csub(a1,a3);
  float2 t3r;
  if constexpr (SIGN < 0) t3r = make_float2(t3.y, -t3.x); else t3r = make_float2(-t3.y, t3.x);
  a0=cadd(t0,t2); a1=cadd(t1,t3r); a2=csub(t0,t2); a3=csub(t1,t3r);
}

template<int SIGN>
__device__ __forceinline__ void radix4_tw(float2& a0, float2& a1, float2& a2, float2& a3, float2 w){
  if constexpr (SIGN > 0) w.y = -w.y;
  float2 w2 = cmul(w, w);
  float2 w3 = cmul(w, w2);
  a1 = cmul(a1, w); a2 = cmul(a2, w2); a3 = cmul(a3, w3);
  radix4_nt<SIGN>(a0, a1, a2, a3);
}

__device__ __forceinline__ float2 twf(int e){
  float s, c;
  __sincosf(-2.0f*PI_F*(float)e*(1.0f/256.0f), &s, &c);
  return make_float2(c, s);
}

// Single 256-pt Stockham radix-4 FFT, wave-private scratch b.
template<int SIGN>
__device__ __forceinline__ void fft256(float2* b, int j,
                                       float2 wA, float2 wB, float2 wC,
                                       float2& x0, float2& x1, float2& x2, float2& x3){
  radix4_nt<SIGN>(x0,x1,x2,x3);
  b[SWZ(4*j)]=x0; b[SWZ(4*j+1)]=x1; b[SWZ(4*j+2)]=x2; b[SWZ(4*j+3)]=x3;
  x0=b[SWZ(j)]; x1=b[SWZ(j+64)]; x2=b[SWZ(j+128)]; x3=b[SWZ(j+192)];
  radix4_tw<SIGN>(x0,x1,x2,x3, wA);
  { int i=((j>>2)<<4)+(j&3); b[SWZ(i)]=x0; b[SWZ(i+4)]=x1; b[SWZ(i+8)]=x2; b[SWZ(i+12)]=x3; }
  x0=b[SWZ(j)]; x1=b[SWZ(j+64)]; x2=b[SWZ(j+128)]; x3=b[SWZ(j+192)];
  radix4_tw<SIGN>(x0,x1,x2,x3, wB);
  { int i=((j>>4)<<6)+(j&15); b[SWZ(i)]=x0; b[SWZ(i+16)]=x1; b[SWZ(i+32)]=x2; b[SWZ(i+48)]=x3; }
  x0=b[SWZ(j)]; x1=b[SWZ(j+64)]; x2=b[SWZ(j+128)]; x3=b[SWZ(j+192)];
  radix4_tw<SIGN>(x0,x1,x2,x3, wC);
}

// Two independent FFTs, stage-interleaved (r8-r12, verified).
template<int SIGN>
__device__ __forceinline__ void fft256x2(float2* bA, float2* bB, int j,
    float2 wA, float2 wB, float2 wC,
    float2& a0, float2& a1, float2& a2, float2& a3,
    float2& b0, float2& b1, float2& b2, float2& b3){
  radix4_nt<SIGN>(a0,a1,a2,a3); radix4_nt<SIGN>(b0,b1,b2,b3);
  bA[SWZ(4*j)]=a0; bA[SWZ(4*j+1)]=a1; bA[SWZ(4*j+2)]=a2; bA[SWZ(4*j+3)]=a3;
  bB[SWZ(4*j)]=b0; bB[SWZ(4*j+1)]=b1; bB[SWZ(4*j+2)]=b2; bB[SWZ(4*j+3)]=b3;
  a0=bA[SWZ(j)]; a1=bA[SWZ(j+64)]; a2=bA[SWZ(j+128)]; a3=bA[SWZ(j+192)];
  b0=bB[SWZ(j)]; b1=bB[SWZ(j+64)]; b2=bB[SWZ(j+128)]; b3=bB[SWZ(j+192)];
  radix4_tw<SIGN>(a0,a1,a2,a3, wA); radix4_tw<SIGN>(b0,b1,b2,b3, wA);
  { int i=((j>>2)<<4)+(j&3);
    bA[SWZ(i)]=a0; bA[SWZ(i+4)]=a1; bA[SWZ(i+8)]=a2; bA[SWZ(i+12)]=a3;
    bB[SWZ(i)]=b0; bB[SWZ(i+4)]=b1; bB[SWZ(i+8)]=b2; bB[SWZ(i+12)]=b3; }
  a0=bA[SWZ(j)]; a1=bA[SWZ(j+64)]; a2=bA[SWZ(j+128)]; a3=bA[SWZ(j+192)];
  b0=bB[SWZ(j)]; b1=bB[SWZ(j+64)]; b2=bB[SWZ(j+128)]; b3=bB[SWZ(j+192)];
  radix4_tw<SIGN>(a0,a1,a2,a3, wB); radix4_tw<SIGN>(b0,b1,b2,b3, wB);
  { int i=((j>>4)<<6)+(j&15);
    bA[SWZ(i)]=a0; bA[SWZ(i+16)]=a1; bA[SWZ(i+32)]=a2; bA[SWZ(i+48)]=a3;
    bB[SWZ(i)]=b0; bB[SWZ(i+16)]=b1; bB[SWZ(i+32)]=b2; bB[SWZ(i+48)]=b3; }
  a0=bA[SWZ(j)]; a1=bA[SWZ(j+64)]; a2=bA[SWZ(j+128)]; a3=bA[SWZ(j+192)];
  b0=bB[SWZ(j)]; b1=bB[SWZ(j+64)]; b2=bB[SWZ(j+128)]; b3=bB[SWZ(j+192)];
  radix4_tw<SIGN>(a0,a1,a2,a3, wC); radix4_tw<SIGN>(b0,b1,b2,b3, wC);
}

// Exact-CG scalar chain (Hermitian M -> all scalars real). Verified r10-r12.
__device__ __forceinline__ void cg_chain3(const float* __restrict__ scal, int n,
                                          float rs_f, float rmr_f,
                                          float& alpha, float& beta){
  float mp = 0.f, P2 = 0.f, rs_prev = 1.f;
  alpha = 0.f; beta = 0.f;
  for (int k = 0; k < n; k++){
    float rsk  = (k == n-1) ? rs_f  : scal[k];
    float rmrk = (k == n-1) ? rmr_f : scal[32+k];
    if (k == 0){ beta = 0.f; mp = rmrk; P2 = rsk; }
    else {
      beta = rsk / rs_prev;
      mp = rmrk - 2.f*beta*rsk/alpha + beta*beta*mp;
      P2 = rsk + beta*beta*P2;
    }
    float pap = mp + LAMBDA_F*P2;
    alpha = rsk / pap;
    rs_prev = rsk;
  }
}

// W-combine for one output plane s (wave-uniform s -> no divergence)
__device__ __forceinline__ float2 w_combine(const float* __restrict__ W9, int wi, int s,
                                            float2 v0, float2 v1, float2 v2){
  if (s == 0){
    float d0 = W9[wi];
    float2 o01 = make_float2(W9[wi+3*HW], W9[wi+4*HW]);
    float2 o02 = make_float2(W9[wi+5*HW], W9[wi+6*HW]);
    return cadd(cadd(cscale(v0,d0), cmul(o01,v1)), cmul(o02,v2));
  } else if (s == 1){
    float d1 = W9[wi+HW];
    float2 o01 = make_float2(W9[wi+3*HW], W9[wi+4*HW]);
    float2 o12 = make_float2(W9[wi+7*HW], W9[wi+8*HW]);
    return cadd(cadd(cmulj(o01,v0), cscale(v1,d1)), cmul(o12,v2));
  } else {
    float d2 = W9[wi+2*HW];
    float2 o02 = make_float2(W9[wi+5*HW], W9[wi+6*HW]);
    float2 o12 = make_float2(W9[wi+7*HW], W9[wi+8*HW]);
    return cadd(cadd(cmulj(o02,v0), cmulj(o12,v1)), cscale(v2,d2));
  }
}

// ---------- W9 precompute + zero scal/part (small, 256 blocks)
__global__ __launch_bounds__(256) void k_W9(const float* __restrict__ mask,
                                            const float2* __restrict__ Lt,
                                            float* __restrict__ W9,
                                            float* __restrict__ scal,
                                            float* __restrict__ part){
  int tid = threadIdx.x, u = blockIdx.x;
  if (u == 0){
    if (tid < 128) scal[tid] = 0.0f;
    for (int i = tid; i < NPART_ROWS*1024; i += 256) part[i] = 0.0f;
  }
  int kx = u, ky = tid;
  int mx = (kx + 128) & 255, my = (ky + 128) & 255;
  float d0=0.f,d1=0.f,d2=0.f;
  float2 o01=make_float2(0,0), o02=make_float2(0,0), o12=make_float2(0,0);
  for (int t = 0; t < NT; t++){
    float m = mask[t*HW + my*256 + mx];
    float2 l0 = Lt[t*3+0], l1 = Lt[t*3+1], l2 = Lt[t*3+2];
    d0 += m*(l0.x*l0.x + l0.y*l0.y);
    d1 += m*(l1.x*l1.x + l1.y*l1.y);
    d2 += m*(l2.x*l2.x + l2.y*l2.y);
    o01 = cadd(o01, cscale(cmulj(l0,l1), m));
    o02 = cadd(o02, cscale(cmulj(l0,l2), m));
    o12 = cadd(o12, cscale(cmulj(l1,l2), m));
  }
  const float nrm = 1.0f/65536.0f;
  int idx = kx*256 + ky;
  W9[idx]      = d0*nrm;  W9[idx+HW]   = d1*nrm;  W9[idx+2*HW] = d2*nrm;
  W9[idx+3*HW] = o01.x*nrm; W9[idx+4*HW] = o01.y*nrm;
  W9[idx+5*HW] = o02.x*nrm; W9[idx+6*HW] = o02.y*nrm;
  W9[idx+7*HW] = o12.x*nrm; W9[idx+8*HW] = o12.y*nrm;
}

// ---------- FUSED setup row pass: g_{c,s} = D sum_t conj(L_ts) y[t,c] in regs,
// row-IFFT (-1), transposed write -> bufA [pl][kx][y]. (verified r11/r12)
__global__ __launch_bounds__(512) void k_rows_g(const float2* __restrict__ y,
                                                const float2* __restrict__ Lt,
                                                float2* __restrict__ dst){
  __shared__ float2 T[8][3][256];   // 48 KB
  int tid = threadIdx.x, g = tid >> 6, j = tid & 63;
  float2 wA = twf((j&3)<<4), wB = twf((j&15)<<2), wC = twf(j);
  int ri = blockIdx.x, c = blockIdx.y;
  int row = ri*8 + g;
  float2 acc[3][4];
  #pragma unroll
  for (int s = 0; s < 3; s++)
    #pragma unroll
    for (int q = 0; q < 4; q++) acc[s][q] = make_float2(0,0);
  for (int t = 0; t < NT; t++){
    const float2* yr = y + ((size_t)(t*NC + c))*HW + row*256;
    float2 l0 = Lt[t*3+0], l1 = Lt[t*3+1], l2 = Lt[t*3+2];
    #pragma unroll
    for (int q = 0; q < 4; q++){
      float2 yv = yr[j + 64*q];
      acc[0][q] = cadd(acc[0][q], cmulj(l0, yv));
      acc[1][q] = cadd(acc[1][q], cmulj(l1, yv));
      acc[2][q] = cadd(acc[2][q], cmulj(l2, yv));
    }
  }
  #pragma unroll
  for (int s = 0; s < 3; s++){
    float2 x0, x1, x2, x3;
    {
      float sg0 = ((j + row) & 1) ? -1.0f : 1.0f;
      x0 = cscale(acc[s][0], sg0);
      x1 = cscale(acc[s][1], sg0);
      x2 = cscale(acc[s][2], sg0);
      x3 = cscale(acc[s][3], sg0);
    }
    fft256<-1>(T[g][s], j, wA,wB,wC, x0,x1,x2,x3);
    T[g][s][j]=x0; T[g][s][j+64]=x1; T[g][s][j+128]=x2; T[g][s][j+192]=x3;
  }
  __syncthreads();
  int yo2 = (tid&3)*2, kxo = tid>>2;
  #pragma unroll
  for (int s = 0; s < 3; s++){
    float2* dT = dst + ((size_t)(c*3+s))*HW;
    #pragma unroll
    for (int kb = 0; kb < 2; kb++){
      int kx = kb*128 + kxo;
      float2 a = T[yo2][s][kx], b = T[yo2+1][s][kx];
      *(float4*)(dT + (size_t)kx*256 + ri*8 + yo2) = make_float4(a.x,a.y,b.x,b.y);
    }
  }
}

// ---------- setup col IFFT (-1): bufA [pl][kx][y] contiguous -> bufB row-major
__global__ __launch_bounds__(512) void k_cols_plain(const float2* __restrict__ src,
                                                    float2* __restrict__ dst){
  __shared__ float2 tile[8][256];
  int tid = threadIdx.x, g = tid >> 6, j = tid & 63;
  float2 wA = twf((j&3)<<4), wB = twf((j&15)<<2), wC = twf(j);
  int pl = blockIdx.y, kg = blockIdx.x;
  int kx = kg*8 + g;
  const float2* col = src + (size_t)pl*HW + (size_t)kx*256;
  float2 x0=col[j], x1=col[j+64], x2=col[j+128], x3=col[j+192];
  fft256<-1>(tile[g], j, wA,wB,wC, x0,x1,x2,x3);
  tile[g][j]=x0; tile[g][j+64]=x1; tile[g][j+128]=x2; tile[g][j+192]=x3;
  __syncthreads();
  float2* d = dst + (size_t)pl*HW;
  int kxo2 = (tid&3)*2, yy = tid>>2;
  #pragma unroll
  for (int yb = 0; yb < 2; yb++){
    int yc = yb*128 + yy;
    float2 a = tile[kxo2][yc], b = tile[kxo2+1][yc];
    *(float4*)(d + (size_t)yc*256 + kg*8 + kxo2) = make_float4(a.x,a.y,b.x,b.y);
  }
}

// ---------- b = D*sum_c conj(S_c)*A + lambda*mo ; r0 = b ; z=0 ; rs0 partial
__global__ __launch_bounds__(256) void k_compute_b(const float2* __restrict__ A,
                                                   const float2* __restrict__ sens,
                                                   const float2* __restrict__ mo,
                                                   float2* __restrict__ r,
                                                   float2* __restrict__ z,
                                                   float* __restrict__ part){
  __shared__ float red[4];
  int idx = blockIdx.x*256 + threadIdx.x;
  int s = idx >> 16, pix = idx & (HW-1);
  int xx = pix & 255, yy = pix >> 8;
  float sg = ((xx + yy) & 1) ? -1.0f : 1.0f;
  float2 accv = make_float2(0,0);
  for (int c = 0; c < NC; c++)
    accv = cadd(accv, cmulj(sens[(size_t)c*HW + pix], A[((size_t)(c*3+s))*HW + pix]));
  float2 b = cadd(cscale(accv, sg), cscale(mo[idx], LAMBDA_F));
  r[idx] = b; z[idx] = make_float2(0,0);
  float partv = b.x*b.x + b.y*b.y;
  for (int off = 32; off; off >>= 1) partv += __shfl_down(partv, off);
  int j = threadIdx.x & 63, w = threadIdx.x >> 6;
  if (j == 0) red[w] = partv;
  __syncthreads();
  if (threadIdx.x == 0) part[ROW_RS(0)*1024 + blockIdx.x] = red[0]+red[1]+red[2]+red[3];
}

// ---------- R-FFT kernel: S_c * r -> row FFT(+1) -> bufA transposed [pl][kx][y].
// grid (32 row-tiles, 10 c), 512 thr = 8 waves x 1 row x 3 s. All reads
// contiguous; transpose on the WRITE side (16 B chunks, r8-proven).
__global__ __launch_bounds__(512) void k_rfft(const float2* __restrict__ rbuf,
                                              const float2* __restrict__ sens,
                                              float2* __restrict__ dst){
  __shared__ float2 T[8][3][256];   // 48 KB
  int tid = threadIdx.x, g = tid >> 6, j = tid & 63;
  float2 wA = twf((j&3)<<4), wB = twf((j&15)<<2), wC = twf(j);
  int ri = blockIdx.x, c = blockIdx.y;
  int row = ri*8 + g;
  const float2* Sc = sens + (size_t)c*HW + row*256;
  float2 sv[4];
  #pragma unroll
  for (int q = 0; q < 4; q++) sv[q] = Sc[j + 64*q];
  #pragma unroll
  for (int s = 0; s < 3; s++){
    const float2* rr = rbuf + (size_t)s*HW + row*256;
    float2 x0 = cmul(sv[0], rr[j]);
    float2 x1 = cmul(sv[1], rr[j+64]);
    float2 x2 = cmul(sv[2], rr[j+128]);
    float2 x3 = cmul(sv[3], rr[j+192]);
    fft256<1>(T[g][s], j, wA,wB,wC, x0,x1,x2,x3);
    T[g][s][j]=x0; T[g][s][j+64]=x1; T[g][s][j+128]=x2; T[g][s][j+192]=x3;
  }
  __syncthreads();
  int yo2 = (tid&3)*2, kxo = tid>>2;
  #pragma unroll
  for (int s = 0; s < 3; s++){
    float2* dT = dst + ((size_t)(c*3+s))*HW;
    #pragma unroll
    for (int kb = 0; kb < 2; kb++){
      int kx = kb*128 + kxo;
      float2 a = T[yo2][s][kx], b = T[yo2+1][s][kx];
      *(float4*)(dT + (size_t)kx*256 + ri*8 + yo2) = make_float4(a.x,a.y,b.x,b.y);
    }
  }
}

// ---------- COL kernel: bufA transposed -> CONTIGUOUS column reads -> col FFT(+1)
// -> U = W V (+ rMr Parseval) -> col IFFT(-1) -> row-major 32 B-chunk writes.
// grid (64 kx-groups of 4, 10 c) = 640 blocks, 384 thr = 6 waves (2 cols each).
__global__ __launch_bounds__(384) void k_colW(const float2* __restrict__ bufA,
                                              float2* __restrict__ bufB,
                                              const float* __restrict__ W9,
                                              float* __restrict__ part, int iter){
  __shared__ float2 T[12][256];   // 24 KB: [s*4 + local_col][row]
  __shared__ float redp[6];
  int tid = threadIdx.x, w = tid >> 6, j = tid & 63;
  float2 wA = twf((j&3)<<4), wB = twf((j&15)<<2), wC = twf(j);
  int kg = blockIdx.x, c = blockIdx.y;
  int s = w >> 1, kxp = w & 1;
  int kxl0 = kxp*2, kxl1 = kxl0 + 1;
  int kx0 = kg*4 + kxl0, kx1 = kg*4 + kxl1;

  // --- direct contiguous column reads + col FFT(+1), 2 columns per wave
  {
    const float2* colA = bufA + ((size_t)(c*3+s))*HW + (size_t)kx0*256;
    const float2* colB = bufA + ((size_t)(c*3+s))*HW + (size_t)kx1*256;
    float2 a0=colA[j], a1=colA[j+64], a2=colA[j+128], a3=colA[j+192];
    float2 b0=colB[j], b1=colB[j+64], b2=colB[j+128], b3=colB[j+192];
    fft256x2<1>(T[s*4+kxl0], T[s*4+kxl1], j, wA,wB,wC, a0,a1,a2,a3, b0,b1,b2,b3);
    T[s*4+kxl0][j]=a0; T[s*4+kxl0][j+64]=a1; T[s*4+kxl0][j+128]=a2; T[s*4+kxl0][j+192]=a3;
    T[s*4+kxl1][j]=b0; T[s*4+kxl1][j+64]=b1; T[s*4+kxl1][j+128]=b2; T[s*4+kxl1][j+192]=b3;
  }
  __syncthreads();

  // --- U = W V + Parseval rMr partial (Re only; exact-math Im sums to 0)
  float2 UA[4], UB[4];
  float pr = 0.f;
  #pragma unroll
  for (int q = 0; q < 4; q++){
    int k = j + 64*q;
    {
      float2 v0 = T[0+kxl0][k], v1 = T[4+kxl0][k], v2 = T[8+kxl0][k];
      float2 U = w_combine(W9, kx0*256 + k, s, v0, v1, v2);
      UA[q] = U;
      float2 vs = (s==0) ? v0 : ((s==1) ? v1 : v2);
      pr += vs.x*U.x + vs.y*U.y;
    }
    {
      float2 v0 = T[0+kxl1][k], v1 = T[4+kxl1][k], v2 = T[8+kxl1][k];
      float2 U = w_combine(W9, kx1*256 + k, s, v0, v1, v2);
      UB[q] = U;
      float2 vs = (s==0) ? v0 : ((s==1) ? v1 : v2);
      pr += vs.x*U.x + vs.y*U.y;
    }
  }
  __syncthreads();   // all V reads done before T reused as IFFT scratch

  // --- col IFFT(-1)
  {
    float2 a0=UA[0], a1=UA[1], a2=UA[2], a3=UA[3];
    float2 b0=UB[0], b1=UB[1], b2=UB[2], b3=UB[3];
    fft256x2<-1>(T[s*4+kxl0], T[s*4+kxl1], j, wA,wB,wC, a0,a1,a2,a3, b0,b1,b2,b3);
    T[s*4+kxl0][j]=a0; T[s*4+kxl0][j+64]=a1; T[s*4+kxl0][j+128]=a2; T[s*4+kxl0][j+192]=a3;
    T[s*4+kxl1][j]=b0; T[s*4+kxl1][j+64]=b1; T[s*4+kxl1][j+128]=b2; T[s*4+kxl1][j+192]=b3;
  }
  // --- reduce rMr partial
  for (int off = 32; off; off >>= 1) pr += __shfl_down(pr, off);
  if (j == 0) redp[w] = pr;
  __syncthreads();
  if (tid == 0){
    float t = 0.f;
    #pragma unroll
    for (int k = 0; k < 6; k++) t += redp[k];
    part[ROW_RMR(iter)*1024 + c*64 + kg] = t;
  }
  // --- scatter to bufB row-major (32 B chunks, write-side stride)
  #pragma unroll
  for (int yb = 0; yb < 4; yb++){
    int flat = yb*384 + tid;
    int s_out = flat >> 9;
    int rem = flat & 511;
    int kxo2 = (rem >> 8) << 1;
    int yc = rem & 255;
    float2 a = T[s_out*4+kxo2][yc], b = T[s_out*4+kxo2+1][yc];
    float2* d = bufB + ((size_t)(c*3+s_out))*HW;
    *(float4*)(d + (size_t)yc*256 + kg*4 + kxo2) = make_float4(a.x,a.y,b.x,b.y);
  }
}

// ---------- UPDATE kernel (iter >= 1). grid (256 rows, 3 s), 640 thr = 10 waves.
// bufB holds K2(S r_{it-1}); row-IFFT + conj(S) combine = Mr_{it-1}; scalar
// chain -> alpha,beta; p/Mp/z/r updates; rs_it partial. (r11 bigrow minus FFT)
__global__ __launch_bounds__(640) void k_update(const float2* __restrict__ bufB,
                                                const float2* __restrict__ sens,
                                                float2* __restrict__ rbuf,
                                                float2* __restrict__ pbuf,
                                                float2* __restrict__ Mpb,
                                                float2* __restrict__ zbuf,
                                                float* __restrict__ scal,
                                                float* __restrict__ part, int iter){
  __shared__ float2 scratch[10][256];
  __shared__ float redv[10];
  __shared__ float sA[2];
  int tid = threadIdx.x, w = tid >> 6, j = tid & 63;
  float2 wA = twf((j&3)<<4), wB = twf((j&15)<<2), wC = twf(j);
  int row = blockIdx.x, s = blockIdx.y;

  // --- reduce fresh scalar partials: rs_{it-1} (768) and rMr_{it-1} (640)
  int rowsel[2] = { ROW_RS(iter-1), ROW_RMR(iter-1) };
  #pragma unroll
  for (int q = 0; q < 2; q++){
    const float* P = part + rowsel[q]*1024;
    float v = P[tid] + ((tid < 384) ? P[tid+640] : 0.f);
    for (int off = 32; off; off >>= 1) v += __shfl_down(v, off);
    if (j == 0) redv[w] = v;
    __syncthreads();
    if (tid == 0){
      float t = 0.f;
      #pragma unroll
      for (int k = 0; k < 10; k++) t += redv[k];
      sA[q] = t;
    }
    __syncthreads();
  }
  float alpha, beta;
  cg_chain3(scal, iter, sA[0], sA[1], alpha, beta);
  if (blockIdx.x == 0 && blockIdx.y == 0 && tid == 0){
    scal[iter-1]    = sA[0];
    scal[32+iter-1] = sA[1];
  }

  // --- phase 1: row IFFT of bufB per coil + conj(S)
  {
    int c = w;
    const float2* src = bufB + ((size_t)(c*3+s))*HW + row*256;
    float2 x0=src[j], x1=src[j+64], x2=src[j+128], x3=src[j+192];
    fft256<-1>(scratch[c], j, wA,wB,wC, x0,x1,x2,x3);
    const float2* Sc = sens + (size_t)c*HW + row*256;
    scratch[c][j]     = cmulj(Sc[j],     x0);
    scratch[c][j+64]  = cmulj(Sc[j+64],  x1);
    scratch[c][j+128] = cmulj(Sc[j+128], x2);
    scratch[c][j+192] = cmulj(Sc[j+192], x3);
  }
  __syncthreads();
  // --- phase 2: combine -> Mr; CG updates (threads 0..255)
  if (tid < 256){
    int k = tid;
    float2 Mr = make_float2(0,0);
    #pragma unroll
    for (int c = 0; c < NC; c++) Mr = cadd(Mr, scratch[c][k]);
    size_t ob = (size_t)s*HW + row*256 + k;
    float2 rold = rbuf[ob];
    float2 pcur, Mpc;
    if (iter == 1){ pcur = rold; Mpc = Mr; }
    else {
      pcur = cadd(rold, cscale(pbuf[ob], beta));
      Mpc  = cadd(Mr,   cscale(Mpb[ob],  beta));
    }
    Mpb[ob]  = Mpc;
    pbuf[ob] = pcur;
    float2 Ap = cadd(Mpc, cscale(pcur, LAMBDA_F));
    float2 zo = zbuf[ob];
    zbuf[ob] = make_float2(zo.x + alpha*pcur.x, zo.y + alpha*pcur.y);
    float2 rnew = make_float2(rold.x - alpha*Ap.x, rold.y - alpha*Ap.y);
    rbuf[ob] = rnew;
    float pv2 = rnew.x*rnew.x + rnew.y*rnew.y;
    for (int off = 32; off; off >>= 1) pv2 += __shfl_down(pv2, off);
    if (j == 0) redv[w] = pv2;   // w in 0..3 here
  }
  __syncthreads();
  if (tid == 0)
    part[ROW_RS(iter)*1024 + s*256 + row] = redv[0]+redv[1]+redv[2]+redv[3];
}

// ---------- final: reduce rs_9, rMr_9 ; p9 = r9 + beta9*p8 ; z += alpha9*p9
__global__ __launch_bounds__(256) void k_final(float2* __restrict__ z,
                                               const float2* __restrict__ rbuf,
                                               const float2* __restrict__ pbuf,
                                               const float* __restrict__ scal,
                                               const float* __restrict__ part){
  __shared__ float redv[4];
  __shared__ float sA[2];
  int tid = threadIdx.x, w = tid >> 6, j = tid & 63;
  int rowsel[2] = { ROW_RS(9), ROW_RMR(9) };
  #pragma unroll
  for (int q = 0; q < 2; q++){
    const float* P = part + rowsel[q]*1024;
    float v = P[tid] + P[tid+256] + P[tid+512] + P[tid+768];
    for (int off = 32; off; off >>= 1) v += __shfl_down(v, off);
    if (j == 0) redv[w] = v;
    __syncthreads();
    if (tid == 0) sA[q] = redv[0]+redv[1]+redv[2]+redv[3];
    __syncthreads();
  }
  float alpha, beta;
  cg_chain3(scal, 10, sA[0], sA[1], alpha, beta);
  int idx = blockIdx.x*256 + tid;
  float2 r9 = rbuf[idx], p8 = pbuf[idx];
  float2 p9 = cadd(r9, cscale(p8, beta));
  float2 zo = z[idx];
  z[idx] = make_float2(zo.x + alpha*p9.x, zo.y + alpha*p9.y);
}

extern "C" void kernel_launch(void* const* d_in, const int* in_sizes, int n_in,
                              void* d_out, int out_size, void* d_ws, size_t ws_size,
                              hipStream_t stream){
  const float2* y    = (const float2*)d_in[0];
  const float2* mo   = (const float2*)d_in[1];
  const float2* sens = (const float2*)d_in[2];
  const float2* Lt   = (const float2*)d_in[3];
  const float*  mask = (const float*)d_in[4];

  float* w = (float*)d_ws;
  float*  scal = w;                                   // 128 floats (rs chain + rMr chain)
  float*  part = w + 128;                             // 26*1024 floats
  float*  W9   = part + NPART_ROWS*1024;              // 9*HW floats
  float2* bufA = (float2*)(W9 + 9*HW);                // 30 planes TRANSPOSED k-space
  float2* bufB = bufA + (size_t)30*HW;                // 30 planes row-major
  float2* rb   = bufB + (size_t)30*HW;                // 3 planes residual
  float2* pb   = rb + (size_t)3*HW;                   // 3 planes direction
  float2* Mpb  = pb + (size_t)3*HW;                   // 3 planes M*p recurrence
  float2* z    = (float2*)d_out;

  // setup (fused): W9 ; g+rowIFFT->bufA_T ; colIFFT->bufB(A) ; b -> r0,z,rs0
  k_W9<<<256, 256, 0, stream>>>(mask, Lt, W9, scal, part);
  k_rows_g<<<dim3(32, 10), 512, 0, stream>>>(y, Lt, bufA);
  k_cols_plain<<<dim3(32, 30), 512, 0, stream>>>(bufA, bufB);
  k_compute_b<<<768, 256, 0, stream>>>(bufB, sens, mo, rb, z, part);

  // CG loop: rfft -> colW -> update (3 kernels/iter, all reads contiguous)
  for (int it = 0; it < 10; it++){
    k_rfft<<<dim3(32, 10), 512, 0, stream>>>(rb, sens, bufA);
    k_colW<<<dim3(64, 10), 384, 0, stream>>>(bufA, bufB, W9, part, it);
    if (it < 9)
      k_update<<<dim3(256, 3), 640, 0, stream>>>(bufB, sens, rb, pb, Mpb, z, scal, part, it+1);
  }
  k_final<<<768, 256, 0, stream>>>(z, rb, pb, scal, part);
}

// Round 15
// 467.992 us; speedup vs baseline: 1.3437x; 1.0577x over previous
//
#include <hip/hip_runtime.h>
#include <hip/hip_fp16.h>
#include <math.h>

#define HW 65536
#define NC 10
#define NT 12
#define LAMBDA_F 0.05f
#define PI_F 3.14159265358979323846f
// XOR-swizzle for wave-private LDS fft scratch
#define SWZ(i) ((i) ^ ((i) >> 4))
// part buffer rows (1024 floats each)
#define ROW_RS(it)  (it)            // rs_it partials: rows 0..9 (768 entries)
#define ROW_RMR(it) (16 + (it))     // rMr_it partials: rows 16..25 (640 entries)
#define NPART_ROWS 26
// fp16 staging scales: rfft applies 1/256; W9 carries 1/256 (net 1/65536);
// bufB16 written with extra 1/32 purely for fp16 range, undone in k_update.
#define RF_SCALE (1.0f/256.0f)
#define BW_SCALE (1.0f/32.0f)
#define BW_INV   32.0f

__device__ __forceinline__ float2 cadd(float2 a, float2 b){ return make_float2(a.x+b.x, a.y+b.y); }
__device__ __forceinline__ float2 csub(float2 a, float2 b){ return make_float2(a.x-b.x, a.y-b.y); }
__device__ __forceinline__ float2 cmul(float2 a, float2 b){ return make_float2(a.x*b.x-a.y*b.y, a.x*b.y+a.y*b.x); }
// conj(a)*b
__device__ __forceinline__ float2 cmulj(float2 a, float2 b){ return make_float2(a.x*b.x+a.y*b.y, a.x*b.y-a.y*b.x); }
__device__ __forceinline__ float2 cscale(float2 a, float s){ return make_float2(a.x*s, a.y*s); }
__device__ __forceinline__ __half2 f2h(float2 v){ return __floats2half2_rn(v.x, v.y); }
__device__ __forceinline__ float2 h2f(__half2 h){ return __half22float2(h); }

template<int SIGN>
__device__ __forceinline__ void radix4_nt(float2& a0, float2& a1, float2& a2, float2& a3){
  float2 t0=cadd(a0,a2), t1=csub(a0,a2), t2=cadd(a1,a3), t3=csub(a1,a3);
  float2 t3r;
  if constexpr (SIGN < 0) t3r = make_float2(t3.y, -t3.x); else t3r = make_float2(-t3.y, t3.x);
  a0=cadd(t0,t2); a1=cadd(t1,t3r); a2=csub(t0,t2); a3=csub(t1,t3r);
}

template<int SIGN>
__device__ __forceinline__ void radix4_tw(float2& a0, float2& a1, float2& a2, float2& a3, float2 w){
  if constexpr (SIGN > 0) w.y = -w.y;
  float2 w2 = cmul(w, w);
  float2 w3 = cmul(w, w2);
  a1 = cmul(a1, w); a2 = cmul(a2, w2); a3 = cmul(a3, w3);
  radix4_nt<SIGN>(a0, a1, a2, a3);
}

__device__ __forceinline__ float2 twf(int e){
  float s, c;
  __sincosf(-2.0f*PI_F*(float)e*(1.0f/256.0f), &s, &c);
  return make_float2(c, s);
}

// Single 256-pt Stockham radix-4 FFT, wave-private scratch b.
template<int SIGN>
__device__ __forceinline__ void fft256(float2* b, int j,
                                       float2 wA, float2 wB, float2 wC,
                                       float2& x0, float2& x1, float2& x2, float2& x3){
  radix4_nt<SIGN>(x0,x1,x2,x3);
  b[SWZ(4*j)]=x0; b[SWZ(4*j+1)]=x1; b[SWZ(4*j+2)]=x2; b[SWZ(4*j+3)]=x3;
  x0=b[SWZ(j)]; x1=b[SWZ(j+64)]; x2=b[SWZ(j+128)]; x3=b[SWZ(j+192)];
  radix4_tw<SIGN>(x0,x1,x2,x3, wA);
  { int i=((j>>2)<<4)+(j&3); b[SWZ(i)]=x0; b[SWZ(i+4)]=x1; b[SWZ(i+8)]=x2; b[SWZ(i+12)]=x3; }
  x0=b[SWZ(j)]; x1=b[SWZ(j+64)]; x2=b[SWZ(j+128)]; x3=b[SWZ(j+192)];
  radix4_tw<SIGN>(x0,x1,x2,x3, wB);
  { int i=((j>>4)<<6)+(j&15); b[SWZ(i)]=x0; b[SWZ(i+16)]=x1; b[SWZ(i+32)]=x2; b[SWZ(i+48)]=x3; }
  x0=b[SWZ(j)]; x1=b[SWZ(j+64)]; x2=b[SWZ(j+128)]; x3=b[SWZ(j+192)];
  radix4_tw<SIGN>(x0,x1,x2,x3, wC);
}

// Two independent FFTs, stage-interleaved (r8-r13, verified).
template<int SIGN>
__device__ __forceinline__ void fft256x2(float2* bA, float2* bB, int j,
    float2 wA, float2 wB, float2 wC,
    float2& a0, float2& a1, float2& a2, float2& a3,
    float2& b0, float2& b1, float2& b2, float2& b3){
  radix4_nt<SIGN>(a0,a1,a2,a3); radix4_nt<SIGN>(b0,b1,b2,b3);
  bA[SWZ(4*j)]=a0; bA[SWZ(4*j+1)]=a1; bA[SWZ(4*j+2)]=a2; bA[SWZ(4*j+3)]=a3;
  bB[SWZ(4*j)]=b0; bB[SWZ(4*j+1)]=b1; bB[SWZ(4*j+2)]=b2; bB[SWZ(4*j+3)]=b3;
  a0=bA[SWZ(j)]; a1=bA[SWZ(j+64)]; a2=bA[SWZ(j+128)]; a3=bA[SWZ(j+192)];
  b0=bB[SWZ(j)]; b1=bB[SWZ(j+64)]; b2=bB[SWZ(j+128)]; b3=bB[SWZ(j+192)];
  radix4_tw<SIGN>(a0,a1,a2,a3, wA); radix4_tw<SIGN>(b0,b1,b2,b3, wA);
  { int i=((j>>2)<<4)+(j&3);
    bA[SWZ(i)]=a0; bA[SWZ(i+4)]=a1; bA[SWZ(i+8)]=a2; bA[SWZ(i+12)]=a3;
    bB[SWZ(i)]=b0; bB[SWZ(i+4)]=b1; bB[SWZ(i+8)]=b2; bB[SWZ(i+12)]=b3; }
  a0=bA[SWZ(j)]; a1=bA[SWZ(j+64)]; a2=bA[SWZ(j+128)]; a3=bA[SWZ(j+192)];
  b0=bB[SWZ(j)]; b1=bB[SWZ(j+64)]; b2=bB[SWZ(j+128)]; b3=bB[SWZ(j+192)];
  radix4_tw<SIGN>(a0,a1,a2,a3, wB); radix4_tw<SIGN>(b0,b1,b2,b3, wB);
  { int i=((j>>4)<<6)+(j&15);
    bA[SWZ(i)]=a0; bA[SWZ(i+16)]=a1; bA[SWZ(i+32)]=a2; bA[SWZ(i+48)]=a3;
    bB[SWZ(i)]=b0; bB[SWZ(i+16)]=b1; bB[SWZ(i+32)]=b2; bB[SWZ(i+48)]=b3; }
  a0=bA[SWZ(j)]; a1=bA[SWZ(j+64)]; a2=bA[SWZ(j+128)]; a3=bA[SWZ(j+192)];
  b0=bB[SWZ(j)]; b1=bB[SWZ(j+64)]; b2=bB[SWZ(j+128)]; b3=bB[SWZ(j+192)];
  radix4_tw<SIGN>(a0,a1,a2,a3, wC); radix4_tw<SIGN>(b0,b1,b2,b3, wC);
}

// Exact-CG scalar chain (Hermitian M -> all scalars real). Verified r10-r13.
__device__ __forceinline__ void cg_chain3(const float* __restrict__ scal, int n,
                                          float rs_f, float rmr_f,
                                          float& alpha, float& beta){
  float mp = 0.f, P2 = 0.f, rs_prev = 1.f;
  alpha = 0.f; beta = 0.f;
  for (int k = 0; k < n; k++){
    float rsk  = (k == n-1) ? rs_f  : scal[k];
    float rmrk = (k == n-1) ? rmr_f : scal[32+k];
    if (k == 0){ beta = 0.f; mp = rmrk; P2 = rsk; }
    else {
      beta = rsk / rs_prev;
      mp = rmrk - 2.f*beta*rsk/alpha + beta*beta*mp;
      P2 = rsk + beta*beta*P2;
    }
    float pap = mp + LAMBDA_F*P2;
    alpha = rsk / pap;
    rs_prev = rsk;
  }
}

// W-combine for one output plane s (wave-uniform s -> no divergence)
__device__ __forceinline__ float2 w_combine(const float* __restrict__ W9, int wi, int s,
                                            float2 v0, float2 v1, float2 v2){
  if (s == 0){
    float d0 = W9[wi];
    float2 o01 = make_float2(W9[wi+3*HW], W9[wi+4*HW]);
    float2 o02 = make_float2(W9[wi+5*HW], W9[wi+6*HW]);
    return cadd(cadd(cscale(v0,d0), cmul(o01,v1)), cmul(o02,v2));
  } else if (s == 1){
    float d1 = W9[wi+HW];
    float2 o01 = make_float2(W9[wi+3*HW], W9[wi+4*HW]);
    float2 o12 = make_float2(W9[wi+7*HW], W9[wi+8*HW]);
    return cadd(cadd(cmulj(o01,v0), cscale(v1,d1)), cmul(o12,v2));
  } else {
    float d2 = W9[wi+2*HW];
    float2 o02 = make_float2(W9[wi+5*HW], W9[wi+6*HW]);
    float2 o12 = make_float2(W9[wi+7*HW], W9[wi+8*HW]);
    return cadd(cadd(cmulj(o02,v0), cmulj(o12,v1)), cscale(v2,d2));
  }
}

// ---------- W9 precompute + zero scal/part (small, 256 blocks)
// NOTE: nrm = 1/256 (the other 1/256 is applied at rfft input for fp16 range).
__global__ __launch_bounds__(256) void k_W9(const float* __restrict__ mask,
                                            const float2* __restrict__ Lt,
                                            float* __restrict__ W9,
                                            float* __restrict__ scal,
                                            float* __restrict__ part){
  int tid = threadIdx.x, u = blockIdx.x;
  if (u == 0){
    if (tid < 128) scal[tid] = 0.0f;
    for (int i = tid; i < NPART_ROWS*1024; i += 256) part[i] = 0.0f;
  }
  int kx = u, ky = tid;
  int mx = (kx + 128) & 255, my = (ky + 128) & 255;
  float d0=0.f,d1=0.f,d2=0.f;
  float2 o01=make_float2(0,0), o02=make_float2(0,0), o12=make_float2(0,0);
  for (int t = 0; t < NT; t++){
    float m = mask[t*HW + my*256 + mx];
    float2 l0 = Lt[t*3+0], l1 = Lt[t*3+1], l2 = Lt[t*3+2];
    d0 += m*(l0.x*l0.x + l0.y*l0.y);
    d1 += m*(l1.x*l1.x + l1.y*l1.y);
    d2 += m*(l2.x*l2.x + l2.y*l2.y);
    o01 = cadd(o01, cscale(cmulj(l0,l1), m));
    o02 = cadd(o02, cscale(cmulj(l0,l2), m));
    o12 = cadd(o12, cscale(cmulj(l1,l2), m));
  }
  const float nrm = 1.0f/256.0f;
  int idx = kx*256 + ky;
  W9[idx]      = d0*nrm;  W9[idx+HW]   = d1*nrm;  W9[idx+2*HW] = d2*nrm;
  W9[idx+3*HW] = o01.x*nrm; W9[idx+4*HW] = o01.y*nrm;
  W9[idx+5*HW] = o02.x*nrm; W9[idx+6*HW] = o02.y*nrm;
  W9[idx+7*HW] = o12.x*nrm; W9[idx+8*HW] = o12.y*nrm;
}

// ---------- FUSED setup row pass: g_{c,s} = D sum_t conj(L_ts) y[t,c] in regs,
// row-IFFT (-1), transposed write -> bufA fp32 [pl][kx][y]. (verified r11-r13)
__global__ __launch_bounds__(512) void k_rows_g(const float2* __restrict__ y,
                                                const float2* __restrict__ Lt,
                                                float2* __restrict__ dst){
  __shared__ float2 T[8][3][256];   // 48 KB
  int tid = threadIdx.x, g = tid >> 6, j = tid & 63;
  float2 wA = twf((j&3)<<4), wB = twf((j&15)<<2), wC = twf(j);
  int ri = blockIdx.x, c = blockIdx.y;
  int row = ri*8 + g;
  float2 acc[3][4];
  #pragma unroll
  for (int s = 0; s < 3; s++)
    #pragma unroll
    for (int q = 0; q < 4; q++) acc[s][q] = make_float2(0,0);
  for (int t = 0; t < NT; t++){
    const float2* yr = y + ((size_t)(t*NC + c))*HW + row*256;
    float2 l0 = Lt[t*3+0], l1 = Lt[t*3+1], l2 = Lt[t*3+2];
    #pragma unroll
    for (int q = 0; q < 4; q++){
      float2 yv = yr[j + 64*q];
      acc[0][q] = cadd(acc[0][q], cmulj(l0, yv));
      acc[1][q] = cadd(acc[1][q], cmulj(l1, yv));
      acc[2][q] = cadd(acc[2][q], cmulj(l2, yv));
    }
  }
  #pragma unroll
  for (int s = 0; s < 3; s++){
    float2 x0, x1, x2, x3;
    {
      float sg0 = ((j + row) & 1) ? -1.0f : 1.0f;
      x0 = cscale(acc[s][0], sg0);
      x1 = cscale(acc[s][1], sg0);
      x2 = cscale(acc[s][2], sg0);
      x3 = cscale(acc[s][3], sg0);
    }
    fft256<-1>(T[g][s], j, wA,wB,wC, x0,x1,x2,x3);
    T[g][s][j]=x0; T[g][s][j+64]=x1; T[g][s][j+128]=x2; T[g][s][j+192]=x3;
  }
  __syncthreads();
  int yo2 = (tid&3)*2, kxo = tid>>2;
  #pragma unroll
  for (int s = 0; s < 3; s++){
    float2* dT = dst + ((size_t)(c*3+s))*HW;
    #pragma unroll
    for (int kb = 0; kb < 2; kb++){
      int kx = kb*128 + kxo;
      float2 a = T[yo2][s][kx], b = T[yo2+1][s][kx];
      *(float4*)(dT + (size_t)kx*256 + ri*8 + yo2) = make_float4(a.x,a.y,b.x,b.y);
    }
  }
}

// ---------- setup col IFFT (-1): bufA fp32 [pl][kx][y] contiguous -> bufB fp32
__global__ __launch_bounds__(512) void k_cols_plain(const float2* __restrict__ src,
                                                    float2* __restrict__ dst){
  __shared__ float2 tile[8][256];
  int tid = threadIdx.x, g = tid >> 6, j = tid & 63;
  float2 wA = twf((j&3)<<4), wB = twf((j&15)<<2), wC = twf(j);
  int pl = blockIdx.y, kg = blockIdx.x;
  int kx = kg*8 + g;
  const float2* col = src + (size_t)pl*HW + (size_t)kx*256;
  float2 x0=col[j], x1=col[j+64], x2=col[j+128], x3=col[j+192];
  fft256<-1>(tile[g], j, wA,wB,wC, x0,x1,x2,x3);
  tile[g][j]=x0; tile[g][j+64]=x1; tile[g][j+128]=x2; tile[g][j+192]=x3;
  __syncthreads();
  float2* d = dst + (size_t)pl*HW;
  int kxo2 = (tid&3)*2, yy = tid>>2;
  #pragma unroll
  for (int yb = 0; yb < 2; yb++){
    int yc = yb*128 + yy;
    float2 a = tile[kxo2][yc], b = tile[kxo2+1][yc];
    *(float4*)(d + (size_t)yc*256 + kg*8 + kxo2) = make_float4(a.x,a.y,b.x,b.y);
  }
}

// ---------- b = D*sum_c conj(S_c)*A + lambda*mo ; r0 = b ; z=0 ; rs0 partial
__global__ __launch_bounds__(256) void k_compute_b(const float2* __restrict__ A,
                                                   const float2* __restrict__ sens,
                                                   const float2* __restrict__ mo,
                                                   float2* __restrict__ r,
                                                   float2* __restrict__ z,
                                                   float* __restrict__ part){
  __shared__ float red[4];
  int idx = blockIdx.x*256 + threadIdx.x;
  int s = idx >> 16, pix = idx & (HW-1);
  int xx = pix & 255, yy = pix >> 8;
  float sg = ((xx + yy) & 1) ? -1.0f : 1.0f;
  float2 accv = make_float2(0,0);
  for (int c = 0; c < NC; c++)
    accv = cadd(accv, cmulj(sens[(size_t)c*HW + pix], A[((size_t)(c*3+s))*HW + pix]));
  float2 b = cadd(cscale(accv, sg), cscale(mo[idx], LAMBDA_F));
  r[idx] = b; z[idx] = make_float2(0,0);
  float partv = b.x*b.x + b.y*b.y;
  for (int off = 32; off; off >>= 1) partv += __shfl_down(partv, off);
  int j = threadIdx.x & 63, w = threadIdx.x >> 6;
  if (j == 0) red[w] = partv;
  __syncthreads();
  if (threadIdx.x == 0) part[ROW_RS(0)*1024 + blockIdx.x] = red[0]+red[1]+red[2]+red[3];
}

// ---------- R-FFT kernel: (S_c * r)*RF_SCALE -> row FFT(+1) -> bufA16 transposed
// [pl][kx][y] fp16. All reads contiguous; 16B-chunk transposed writes.
__global__ __launch_bounds__(512) void k_rfft(const float2* __restrict__ rbuf,
                                              const float2* __restrict__ sens,
                                              __half2* __restrict__ dst){
  __shared__ float2 T[8][3][256];   // 48 KB
  int tid = threadIdx.x, g = tid >> 6, j = tid & 63;
  float2 wA = twf((j&3)<<4), wB = twf((j&15)<<2), wC = twf(j);
  int ri = blockIdx.x, c = blockIdx.y;
  int row = ri*8 + g;
  const float2* Sc = sens + (size_t)c*HW + row*256;
  float2 sv[4];
  #pragma unroll
  for (int q = 0; q < 4; q++) sv[q] = cscale(Sc[j + 64*q], RF_SCALE);
  #pragma unroll
  for (int s = 0; s < 3; s++){
    const float2* rr = rbuf + (size_t)s*HW + row*256;
    float2 x0 = cmul(sv[0], rr[j]);
    float2 x1 = cmul(sv[1], rr[j+64]);
    float2 x2 = cmul(sv[2], rr[j+128]);
    float2 x3 = cmul(sv[3], rr[j+192]);
    fft256<1>(T[g][s], j, wA,wB,wC, x0,x1,x2,x3);
    T[g][s][j]=x0; T[g][s][j+64]=x1; T[g][s][j+128]=x2; T[g][s][j+192]=x3;
  }
  __syncthreads();
  // transposed scatter as fp16, 16B chunks (4 y-values per write)
  #pragma unroll
  for (int f = 0; f < 3; f++){
    int flat = f*512 + tid;           // 0..1535
    int s = flat >> 9, rem = flat & 511, kx = rem >> 1, ch = rem & 1;
    float4 pkf;                       // 16B-aligned backing store
    __half2* pk = (__half2*)&pkf;
    #pragma unroll
    for (int rr = 0; rr < 4; rr++) pk[rr] = f2h(T[ch*4+rr][s][kx]);
    __half2* dT = dst + ((size_t)(c*3+s))*HW + (size_t)kx*256 + ri*8 + ch*4;
    *(float4*)dT = pkf;
  }
}

// ---------- COL kernel: bufA16 transposed -> CONTIGUOUS column reads -> col
// FFT(+1) -> U = W V (+ rMr Parseval, x256 scale comp) -> col IFFT(-1) ->
// bufB16 row-major 16B-chunk writes (scaled by BW_SCALE for fp16 range).
__global__ __launch_bounds__(384) void k_colW(const __half2* __restrict__ bufA,
                                              __half2* __restrict__ bufB,
                                              const float* __restrict__ W9,
                                              float* __restrict__ part, int iter){
  __shared__ float2 T[12][256];   // 24 KB: [s*4 + local_col][row]
  __shared__ float redp[6];
  int tid = threadIdx.x, w = tid >> 6, j = tid & 63;
  float2 wA = twf((j&3)<<4), wB = twf((j&15)<<2), wC = twf(j);
  int kg = blockIdx.x, c = blockIdx.y;
  int s = w >> 1, kxp = w & 1;
  int kxl0 = kxp*2, kxl1 = kxl0 + 1;
  int kx0 = kg*4 + kxl0, kx1 = kg*4 + kxl1;

  // --- direct contiguous column reads (fp16) + col FFT(+1), 2 cols per wave
  {
    const __half2* colA = bufA + ((size_t)(c*3+s))*HW + (size_t)kx0*256;
    const __half2* colB = bufA + ((size_t)(c*3+s))*HW + (size_t)kx1*256;
    float2 a0=h2f(colA[j]), a1=h2f(colA[j+64]), a2=h2f(colA[j+128]), a3=h2f(colA[j+192]);
    float2 b0=h2f(colB[j]), b1=h2f(colB[j+64]), b2=h2f(colB[j+128]), b3=h2f(colB[j+192]);
    fft256x2<1>(T[s*4+kxl0], T[s*4+kxl1], j, wA,wB,wC, a0,a1,a2,a3, b0,b1,b2,b3);
    T[s*4+kxl0][j]=a0; T[s*4+kxl0][j+64]=a1; T[s*4+kxl0][j+128]=a2; T[s*4+kxl0][j+192]=a3;
    T[s*4+kxl1][j]=b0; T[s*4+kxl1][j+64]=b1; T[s*4+kxl1][j+128]=b2; T[s*4+kxl1][j+192]=b3;
  }
  __syncthreads();

  // --- U = W V + Parseval rMr partial (Re only)
  float2 UA[4], UB[4];
  float pr = 0.f;
  #pragma unroll
  for (int q = 0; q < 4; q++){
    int k = j + 64*q;
    {
      float2 v0 = T[0+kxl0][k], v1 = T[4+kxl0][k], v2 = T[8+kxl0][k];
      float2 U = w_combine(W9, kx0*256 + k, s, v0, v1, v2);
      UA[q] = U;
      float2 vs = (s==0) ? v0 : ((s==1) ? v1 : v2);
      pr += vs.x*U.x + vs.y*U.y;
    }
    {
      float2 v0 = T[0+kxl1][k], v1 = T[4+kxl1][k], v2 = T[8+kxl1][k];
      float2 U = w_combine(W9, kx1*256 + k, s, v0, v1, v2);
      UB[q] = U;
      float2 vs = (s==0) ? v0 : ((s==1) ? v1 : v2);
      pr += vs.x*U.x + vs.y*U.y;
    }
  }
  __syncthreads();   // all V reads done before T reused as IFFT scratch

  // --- col IFFT(-1)
  {
    float2 a0=UA[0], a1=UA[1], a2=UA[2], a3=UA[3];
    float2 b0=UB[0], b1=UB[1], b2=UB[2], b3=UB[3];
    fft256x2<-1>(T[s*4+kxl0], T[s*4+kxl1], j, wA,wB,wC, a0,a1,a2,a3, b0,b1,b2,b3);
    T[s*4+kxl0][j]=a0; T[s*4+kxl0][j+64]=a1; T[s*4+kxl0][j+128]=a2; T[s*4+kxl0][j+192]=a3;
    T[s*4+kxl1][j]=b0; T[s*4+kxl1][j+64]=b1; T[s*4+kxl1][j+128]=b2; T[s*4+kxl1][j+192]=b3;
  }
  // --- reduce rMr partial (x256 compensates RF_SCALE^2 * W9 scale vs r13)
  for (int off = 32; off; off >>= 1) pr += __shfl_down(pr, off);
  if (j == 0) redp[w] = pr;
  __syncthreads();
  if (tid == 0){
    float t = 0.f;
    #pragma unroll
    for (int k = 0; k < 6; k++) t += redp[k];
    part[ROW_RMR(iter)*1024 + c*64 + kg] = t * 256.0f;
  }
  // --- scatter to bufB16 row-major (16B chunks: 4 kx per write), /32 range scale
  #pragma unroll
  for (int f = 0; f < 2; f++){
    int flat = f*384 + tid;           // 0..767
    int s_out = flat >> 8, yc = flat & 255;
    float4 pkf;                       // 16B-aligned backing store
    __half2* pk = (__half2*)&pkf;
    #pragma unroll
    for (int k4 = 0; k4 < 4; k4++) pk[k4] = f2h(cscale(T[s_out*4+k4][yc], BW_SCALE));
    __half2* d = bufB + ((size_t)(c*3+s_out))*HW + (size_t)yc*256 + kg*4;
    *(float4*)d = pkf;
  }
}

// ---------- UPDATE kernel (iter >= 1). grid (256 rows, 3 s), 640 thr = 10 waves.
// bufB16 holds K2(S r_{it-1})*BW_SCALE; row-IFFT(x BW_INV) + conj(S) combine =
// Mr_{it-1}; scalar chain -> alpha,beta; p/Mp/z/r updates; rs_it partial.
__global__ __launch_bounds__(640) void k_update(const __half2* __restrict__ bufB,
                                                const float2* __restrict__ sens,
                                                float2* __restrict__ rbuf,
                                                float2* __restrict__ pbuf,
                                                float2* __restrict__ Mpb,
                                                float2* __restrict__ zbuf,
                                                float* __restrict__ scal,
                                                float* __restrict__ part, int iter){
  __shared__ float2 scratch[10][256];
  __shared__ float redv[10];
  __shared__ float sA[2];
  int tid = threadIdx.x, w = tid >> 6, j = tid & 63;
  float2 wA = twf((j&3)<<4), wB = twf((j&15)<<2), wC = twf(j);
  int row = blockIdx.x, s = blockIdx.y;

  // --- reduce fresh scalar partials: rs_{it-1} (768) and rMr_{it-1} (640)
  int rowsel[2] = { ROW_RS(iter-1), ROW_RMR(iter-1) };
  #pragma unroll
  for (int q = 0; q < 2; q++){
    const float* P = part + rowsel[q]*1024;
    float v = P[tid] + ((tid < 384) ? P[tid+640] : 0.f);
    for (int off = 32; off; off >>= 1) v += __shfl_down(v, off);
    if (j == 0) redv[w] = v;
    __syncthreads();
    if (tid == 0){
      float t = 0.f;
      #pragma unroll
      for (int k = 0; k < 10; k++) t += redv[k];
      sA[q] = t;
    }
    __syncthreads();
  }
  float alpha, beta;
  cg_chain3(scal, iter, sA[0], sA[1], alpha, beta);
  if (blockIdx.x == 0 && blockIdx.y == 0 && tid == 0){
    scal[iter-1]    = sA[0];
    scal[32+iter-1] = sA[1];
  }

  // --- phase 1: row IFFT of bufB16 per coil (undo BW_SCALE) + conj(S)
  {
    int c = w;
    const __half2* src = bufB + ((size_t)(c*3+s))*HW + row*256;
    float2 x0=cscale(h2f(src[j]),     BW_INV);
    float2 x1=cscale(h2f(src[j+64]),  BW_INV);
    float2 x2=cscale(h2f(src[j+128]), BW_INV);
    float2 x3=cscale(h2f(src[j+192]), BW_INV);
    fft256<-1>(scratch[c], j, wA,wB,wC, x0,x1,x2,x3);
    const float2* Sc = sens + (size_t)c*HW + row*256;
    scratch[c][j]     = cmulj(Sc[j],     x0);
    scratch[c][j+64]  = cmulj(Sc[j+64],  x1);
    scratch[c][j+128] = cmulj(Sc[j+128], x2);
    scratch[c][j+192] = cmulj(Sc[j+192], x3);
  }
  __syncthreads();
  // --- phase 2: combine -> Mr; CG updates (threads 0..255)
  if (tid < 256){
    int k = tid;
    float2 Mr = make_float2(0,0);
    #pragma unroll
    for (int c = 0; c < NC; c++) Mr = cadd(Mr, scratch[c][k]);
    size_t ob = (size_t)s*HW + row*256 + k;
    float2 rold = rbuf[ob];
    float2 pcur, Mpc;
    if (iter == 1){ pcur = rold; Mpc = Mr; }
    else {
      pcur = cadd(rold, cscale(pbuf[ob], beta));
      Mpc  = cadd(Mr,   cscale(Mpb[ob],  beta));
    }
    Mpb[ob]  = Mpc;
    pbuf[ob] = pcur;
    float2 Ap = cadd(Mpc, cscale(pcur, LAMBDA_F));
    float2 zo = zbuf[ob];
    zbuf[ob] = make_float2(zo.x + alpha*pcur.x, zo.y + alpha*pcur.y);
    float2 rnew = make_float2(rold.x - alpha*Ap.x, rold.y - alpha*Ap.y);
    rbuf[ob] = rnew;
    float pv2 = rnew.x*rnew.x + rnew.y*rnew.y;
    for (int off = 32; off; off >>= 1) pv2 += __shfl_down(pv2, off);
    if (j == 0) redv[w] = pv2;   // w in 0..3 here
  }
  __syncthreads();
  if (tid == 0)
    part[ROW_RS(iter)*1024 + s*256 + row] = redv[0]+redv[1]+redv[2]+redv[3];
}

// ---------- final: reduce rs_9, rMr_9 ; p9 = r9 + beta9*p8 ; z += alpha9*p9
__global__ __launch_bounds__(256) void k_final(float2* __restrict__ z,
                                               const float2* __restrict__ rbuf,
                                               const float2* __restrict__ pbuf,
                                               const float* __restrict__ scal,
                                               const float* __restrict__ part){
  __shared__ float redv[4];
  __shared__ float sA[2];
  int tid = threadIdx.x, w = tid >> 6, j = tid & 63;
  int rowsel[2] = { ROW_RS(9), ROW_RMR(9) };
  #pragma unroll
  for (int q = 0; q < 2; q++){
    const float* P = part + rowsel[q]*1024;
    float v = P[tid] + P[tid+256] + P[tid+512] + P[tid+768];
    for (int off = 32; off; off >>= 1) v += __shfl_down(v, off);
    if (j == 0) redv[w] = v;
    __syncthreads();
    if (tid == 0) sA[q] = redv[0]+redv[1]+redv[2]+redv[3];
    __syncthreads();
  }
  float alpha, beta;
  cg_chain3(scal, 10, sA[0], sA[1], alpha, beta);
  int idx = blockIdx.x*256 + tid;
  float2 r9 = rbuf[idx], p8 = pbuf[idx];
  float2 p9 = cadd(r9, cscale(p8, beta));
  float2 zo = z[idx];
  z[idx] = make_float2(zo.x + alpha*p9.x, zo.y + alpha*p9.y);
}

extern "C" void kernel_launch(void* const* d_in, const int* in_sizes, int n_in,
                              void* d_out, int out_size, void* d_ws, size_t ws_size,
                              hipStream_t stream){
  const float2* y    = (const float2*)d_in[0];
  const float2* mo   = (const float2*)d_in[1];
  const float2* sens = (const float2*)d_in[2];
  const float2* Lt   = (const float2*)d_in[3];
  const float*  mask = (const float*)d_in[4];

  float* w = (float*)d_ws;
  float*  scal = w;                                   // 128 floats (rs chain + rMr chain)
  float*  part = w + 128;                             // 26*1024 floats
  float*  W9   = part + NPART_ROWS*1024;              // 9*HW floats
  float2* bufA = (float2*)(W9 + 9*HW);                // 30 planes fp32 (setup only)
  float2* bufB = bufA + (size_t)30*HW;                // 30 planes fp32 (setup only)
  float2* rb   = bufB + (size_t)30*HW;                // 3 planes residual
  float2* pb   = rb + (size_t)3*HW;                   // 3 planes direction
  float2* Mpb  = pb + (size_t)3*HW;                   // 3 planes M*p recurrence
  float2* z    = (float2*)d_out;
  // fp16 staging aliases the (dead after setup) fp32 staging buffers
  __half2* bufA16 = (__half2*)bufA;                   // 30 planes transposed k-space
  __half2* bufB16 = (__half2*)bufB;                   // 30 planes row-major

  // setup (fused, fp32): W9 ; g+rowIFFT->bufA_T ; colIFFT->bufB(A) ; b -> r0,z,rs0
  k_W9<<<256, 256, 0, stream>>>(mask, Lt, W9, scal, part);
  k_rows_g<<<dim3(32, 10), 512, 0, stream>>>(y, Lt, bufA);
  k_cols_plain<<<dim3(32, 30), 512, 0, stream>>>(bufA, bufB);
  k_compute_b<<<768, 256, 0, stream>>>(bufB, sens, mo, rb, z, part);

  // CG loop: rfft -> colW -> update (all reads contiguous, fp16 staging)
  for (int it = 0; it < 10; it++){
    k_rfft<<<dim3(32, 10), 512, 0, stream>>>(rb, sens, bufA16);
    k_colW<<<dim3(64, 10), 384, 0, stream>>>(bufA16, bufB16, W9, part, it);
    if (it < 9)
      k_update<<<dim3(256, 3), 640, 0, stream>>>(bufB16, sens, rb, pb, Mpb, z, scal, part, it+1);
  }
  k_final<<<768, 256, 0, stream>>>(z, rb, pb, scal, part);
}

// Round 16
// 466.718 us; speedup vs baseline: 1.3473x; 1.0027x over previous
//
#include <hip/hip_runtime.h>
#include <hip/hip_fp16.h>
#include <math.h>

#define HW 65536
#define NC 10
#define NT 12
#define LAMBDA_F 0.05f
#define PI_F 3.14159265358979323846f
// XOR-swizzle for wave-private LDS fft scratch
#define SWZ(i) ((i) ^ ((i) >> 4))
// part buffer rows (1024 floats each)
#define ROW_RS(it)  (it)            // rs_it partials: rows 0..9 (768 entries)
#define ROW_RMR(it) (16 + (it))     // rMr_it partials: rows 16..25 (640 entries)
#define NPART_ROWS 26
// fp16 staging scales: rfft applies 1/256; W9 carries 1/256 (net 1/65536);
// bufB16 written with extra 1/32 purely for fp16 range, undone in k_update.
#define RF_SCALE (1.0f/256.0f)
#define BW_SCALE (1.0f/32.0f)
#define BW_INV   32.0f

__device__ __forceinline__ float2 cadd(float2 a, float2 b){ return make_float2(a.x+b.x, a.y+b.y); }
__device__ __forceinline__ float2 csub(float2 a, float2 b){ return make_float2(a.x-b.x, a.y-b.y); }
__device__ __forceinline__ float2 cmul(float2 a, float2 b){ return make_float2(a.x*b.x-a.y*b.y, a.x*b.y+a.y*b.x); }
// conj(a)*b
__device__ __forceinline__ float2 cmulj(float2 a, float2 b){ return make_float2(a.x*b.x+a.y*b.y, a.x*b.y-a.y*b.x); }
__device__ __forceinline__ float2 cscale(float2 a, float s){ return make_float2(a.x*s, a.y*s); }
__device__ __forceinline__ __half2 f2h(float2 v){ return __floats2half2_rn(v.x, v.y); }
__device__ __forceinline__ float2 h2f(__half2 h){ return __half22float2(h); }

template<int SIGN>
__device__ __forceinline__ void radix4_nt(float2& a0, float2& a1, float2& a2, float2& a3){
  float2 t0=cadd(a0,a2), t1=csub(a0,a2), t2=cadd(a1,a3), t3=csub(a1,a3);
  float2 t3r;
  if constexpr (SIGN < 0) t3r = make_float2(t3.y, -t3.x); else t3r = make_float2(-t3.y, t3.x);
  a0=cadd(t0,t2); a1=cadd(t1,t3r); a2=csub(t0,t2); a3=csub(t1,t3r);
}

template<int SIGN>
__device__ __forceinline__ void radix4_tw(float2& a0, float2& a1, float2& a2, float2& a3, float2 w){
  if constexpr (SIGN > 0) w.y = -w.y;
  float2 w2 = cmul(w, w);
  float2 w3 = cmul(w, w2);
  a1 = cmul(a1, w); a2 = cmul(a2, w2); a3 = cmul(a3, w3);
  radix4_nt<SIGN>(a0, a1, a2, a3);
}

__device__ __forceinline__ float2 twf(int e){
  float s, c;
  __sincosf(-2.0f*PI_F*(float)e*(1.0f/256.0f), &s, &c);
  return make_float2(c, s);
}

// Single 256-pt Stockham radix-4 FFT, wave-private scratch b.
template<int SIGN>
__device__ __forceinline__ void fft256(float2* b, int j,
                                       float2 wA, float2 wB, float2 wC,
                                       float2& x0, float2& x1, float2& x2, float2& x3){
  radix4_nt<SIGN>(x0,x1,x2,x3);
  b[SWZ(4*j)]=x0; b[SWZ(4*j+1)]=x1; b[SWZ(4*j+2)]=x2; b[SWZ(4*j+3)]=x3;
  x0=b[SWZ(j)]; x1=b[SWZ(j+64)]; x2=b[SWZ(j+128)]; x3=b[SWZ(j+192)];
  radix4_tw<SIGN>(x0,x1,x2,x3, wA);
  { int i=((j>>2)<<4)+(j&3); b[SWZ(i)]=x0; b[SWZ(i+4)]=x1; b[SWZ(i+8)]=x2; b[SWZ(i+12)]=x3; }
  x0=b[SWZ(j)]; x1=b[SWZ(j+64)]; x2=b[SWZ(j+128)]; x3=b[SWZ(j+192)];
  radix4_tw<SIGN>(x0,x1,x2,x3, wB);
  { int i=((j>>4)<<6)+(j&15); b[SWZ(i)]=x0; b[SWZ(i+16)]=x1; b[SWZ(i+32)]=x2; b[SWZ(i+48)]=x3; }
  x0=b[SWZ(j)]; x1=b[SWZ(j+64)]; x2=b[SWZ(j+128)]; x3=b[SWZ(j+192)];
  radix4_tw<SIGN>(x0,x1,x2,x3, wC);
}

// Two independent FFTs, stage-interleaved (r8-r15, verified).
template<int SIGN>
__device__ __forceinline__ void fft256x2(float2* bA, float2* bB, int j,
    float2 wA, float2 wB, float2 wC,
    float2& a0, float2& a1, float2& a2, float2& a3,
    float2& b0, float2& b1, float2& b2, float2& b3){
  radix4_nt<SIGN>(a0,a1,a2,a3); radix4_nt<SIGN>(b0,b1,b2,b3);
  bA[SWZ(4*j)]=a0; bA[SWZ(4*j+1)]=a1; bA[SWZ(4*j+2)]=a2; bA[SWZ(4*j+3)]=a3;
  bB[SWZ(4*j)]=b0; bB[SWZ(4*j+1)]=b1; bB[SWZ(4*j+2)]=b2; bB[SWZ(4*j+3)]=b3;
  a0=bA[SWZ(j)]; a1=bA[SWZ(j+64)]; a2=bA[SWZ(j+128)]; a3=bA[SWZ(j+192)];
  b0=bB[SWZ(j)]; b1=bB[SWZ(j+64)]; b2=bB[SWZ(j+128)]; b3=bB[SWZ(j+192)];
  radix4_tw<SIGN>(a0,a1,a2,a3, wA); radix4_tw<SIGN>(b0,b1,b2,b3, wA);
  { int i=((j>>2)<<4)+(j&3);
    bA[SWZ(i)]=a0; bA[SWZ(i+4)]=a1; bA[SWZ(i+8)]=a2; bA[SWZ(i+12)]=a3;
    bB[SWZ(i)]=b0; bB[SWZ(i+4)]=b1; bB[SWZ(i+8)]=b2; bB[SWZ(i+12)]=b3; }
  a0=bA[SWZ(j)]; a1=bA[SWZ(j+64)]; a2=bA[SWZ(j+128)]; a3=bA[SWZ(j+192)];
  b0=bB[SWZ(j)]; b1=bB[SWZ(j+64)]; b2=bB[SWZ(j+128)]; b3=bB[SWZ(j+192)];
  radix4_tw<SIGN>(a0,a1,a2,a3, wB); radix4_tw<SIGN>(b0,b1,b2,b3, wB);
  { int i=((j>>4)<<6)+(j&15);
    bA[SWZ(i)]=a0; bA[SWZ(i+16)]=a1; bA[SWZ(i+32)]=a2; bA[SWZ(i+48)]=a3;
    bB[SWZ(i)]=b0; bB[SWZ(i+16)]=b1; bB[SWZ(i+32)]=b2; bB[SWZ(i+48)]=b3; }
  a0=bA[SWZ(j)]; a1=bA[SWZ(j+64)]; a2=bA[SWZ(j+128)]; a3=bA[SWZ(j+192)];
  b0=bB[SWZ(j)]; b1=bB[SWZ(j+64)]; b2=bB[SWZ(j+128)]; b3=bB[SWZ(j+192)];
  radix4_tw<SIGN>(a0,a1,a2,a3, wC); radix4_tw<SIGN>(b0,b1,b2,b3, wC);
}

// Exact-CG scalar chain (Hermitian M -> all scalars real). Verified r10-r15.
__device__ __forceinline__ void cg_chain3(const float* __restrict__ scal, int n,
                                          float rs_f, float rmr_f,
                                          float& alpha, float& beta){
  float mp = 0.f, P2 = 0.f, rs_prev = 1.f;
  alpha = 0.f; beta = 0.f;
  for (int k = 0; k < n; k++){
    float rsk  = (k == n-1) ? rs_f  : scal[k];
    float rmrk = (k == n-1) ? rmr_f : scal[32+k];
    if (k == 0){ beta = 0.f; mp = rmrk; P2 = rsk; }
    else {
      beta = rsk / rs_prev;
      mp = rmrk - 2.f*beta*rsk/alpha + beta*beta*mp;
      P2 = rsk + beta*beta*P2;
    }
    float pap = mp + LAMBDA_F*P2;
    alpha = rsk / pap;
    rs_prev = rsk;
  }
}

// W-combine for one output plane s (wave-uniform s -> no divergence)
__device__ __forceinline__ float2 w_combine(const float* __restrict__ W9, int wi, int s,
                                            float2 v0, float2 v1, float2 v2){
  if (s == 0){
    float d0 = W9[wi];
    float2 o01 = make_float2(W9[wi+3*HW], W9[wi+4*HW]);
    float2 o02 = make_float2(W9[wi+5*HW], W9[wi+6*HW]);
    return cadd(cadd(cscale(v0,d0), cmul(o01,v1)), cmul(o02,v2));
  } else if (s == 1){
    float d1 = W9[wi+HW];
    float2 o01 = make_float2(W9[wi+3*HW], W9[wi+4*HW]);
    float2 o12 = make_float2(W9[wi+7*HW], W9[wi+8*HW]);
    return cadd(cadd(cmulj(o01,v0), cscale(v1,d1)), cmul(o12,v2));
  } else {
    float d2 = W9[wi+2*HW];
    float2 o02 = make_float2(W9[wi+5*HW], W9[wi+6*HW]);
    float2 o12 = make_float2(W9[wi+7*HW], W9[wi+8*HW]);
    return cadd(cadd(cmulj(o02,v0), cmulj(o12,v1)), cscale(v2,d2));
  }
}

// ---------- W9 precompute + sens->fp16 + zero scal/part.
// grid 416: blocks 0..255 = W9 ; blocks 256..415 = sens16 conversion.
__global__ __launch_bounds__(256) void k_W9(const float* __restrict__ mask,
                                            const float2* __restrict__ Lt,
                                            const float2* __restrict__ sens,
                                            float* __restrict__ W9,
                                            __half2* __restrict__ sens16,
                                            float* __restrict__ scal,
                                            float* __restrict__ part){
  int tid = threadIdx.x, u = blockIdx.x;
  if (u >= 256){
    int base = (u - 256) * 4096;
    for (int i = tid; i < 4096; i += 256)
      sens16[base + i] = f2h(sens[base + i]);
    return;
  }
  if (u == 0){
    if (tid < 128) scal[tid] = 0.0f;
    for (int i = tid; i < NPART_ROWS*1024; i += 256) part[i] = 0.0f;
  }
  int kx = u, ky = tid;
  int mx = (kx + 128) & 255, my = (ky + 128) & 255;
  float d0=0.f,d1=0.f,d2=0.f;
  float2 o01=make_float2(0,0), o02=make_float2(0,0), o12=make_float2(0,0);
  for (int t = 0; t < NT; t++){
    float m = mask[t*HW + my*256 + mx];
    float2 l0 = Lt[t*3+0], l1 = Lt[t*3+1], l2 = Lt[t*3+2];
    d0 += m*(l0.x*l0.x + l0.y*l0.y);
    d1 += m*(l1.x*l1.x + l1.y*l1.y);
    d2 += m*(l2.x*l2.x + l2.y*l2.y);
    o01 = cadd(o01, cscale(cmulj(l0,l1), m));
    o02 = cadd(o02, cscale(cmulj(l0,l2), m));
    o12 = cadd(o12, cscale(cmulj(l1,l2), m));
  }
  const float nrm = 1.0f/256.0f;
  int idx = kx*256 + ky;
  W9[idx]      = d0*nrm;  W9[idx+HW]   = d1*nrm;  W9[idx+2*HW] = d2*nrm;
  W9[idx+3*HW] = o01.x*nrm; W9[idx+4*HW] = o01.y*nrm;
  W9[idx+5*HW] = o02.x*nrm; W9[idx+6*HW] = o02.y*nrm;
  W9[idx+7*HW] = o12.x*nrm; W9[idx+8*HW] = o12.y*nrm;
}

// ---------- FUSED setup row pass: g_{c,s} = D sum_t conj(L_ts) y[t,c] in regs,
// row-IFFT (-1), transposed fp16 write -> bufA16 [pl][kx][y].
__global__ __launch_bounds__(512) void k_rows_g(const float2* __restrict__ y,
                                                const float2* __restrict__ Lt,
                                                __half2* __restrict__ dst){
  __shared__ float2 T[8][3][256];   // 48 KB
  int tid = threadIdx.x, g = tid >> 6, j = tid & 63;
  float2 wA = twf((j&3)<<4), wB = twf((j&15)<<2), wC = twf(j);
  int ri = blockIdx.x, c = blockIdx.y;
  int row = ri*8 + g;
  float2 acc[3][4];
  #pragma unroll
  for (int s = 0; s < 3; s++)
    #pragma unroll
    for (int q = 0; q < 4; q++) acc[s][q] = make_float2(0,0);
  for (int t = 0; t < NT; t++){
    const float2* yr = y + ((size_t)(t*NC + c))*HW + row*256;
    float2 l0 = Lt[t*3+0], l1 = Lt[t*3+1], l2 = Lt[t*3+2];
    #pragma unroll
    for (int q = 0; q < 4; q++){
      float2 yv = yr[j + 64*q];
      acc[0][q] = cadd(acc[0][q], cmulj(l0, yv));
      acc[1][q] = cadd(acc[1][q], cmulj(l1, yv));
      acc[2][q] = cadd(acc[2][q], cmulj(l2, yv));
    }
  }
  #pragma unroll
  for (int s = 0; s < 3; s++){
    float2 x0, x1, x2, x3;
    {
      float sg0 = ((j + row) & 1) ? -1.0f : 1.0f;
      x0 = cscale(acc[s][0], sg0);
      x1 = cscale(acc[s][1], sg0);
      x2 = cscale(acc[s][2], sg0);
      x3 = cscale(acc[s][3], sg0);
    }
    fft256<-1>(T[g][s], j, wA,wB,wC, x0,x1,x2,x3);
    T[g][s][j]=x0; T[g][s][j+64]=x1; T[g][s][j+128]=x2; T[g][s][j+192]=x3;
  }
  __syncthreads();
  // transposed scatter as fp16, 16B chunks (4 y-values per write)
  #pragma unroll
  for (int f = 0; f < 3; f++){
    int flat = f*512 + tid;           // 0..1535
    int s = flat >> 9, rem = flat & 511, kx = rem >> 1, ch = rem & 1;
    float4 pkf;                       // 16B-aligned backing store
    __half2* pk = (__half2*)&pkf;
    #pragma unroll
    for (int rr = 0; rr < 4; rr++) pk[rr] = f2h(T[ch*4+rr][s][kx]);
    __half2* dT = dst + ((size_t)(c*3+s))*HW + (size_t)kx*256 + ri*8 + ch*4;
    *(float4*)dT = pkf;
  }
}

// ---------- setup col IFFT (-1): bufA16 [pl][kx][y] contiguous -> bufB16 row-major
__global__ __launch_bounds__(512) void k_cols_plain(const __half2* __restrict__ src,
                                                    __half2* __restrict__ dst){
  __shared__ float2 tile[8][256];
  int tid = threadIdx.x, g = tid >> 6, j = tid & 63;
  float2 wA = twf((j&3)<<4), wB = twf((j&15)<<2), wC = twf(j);
  int pl = blockIdx.y, kg = blockIdx.x;
  int kx = kg*8 + g;
  const __half2* col = src + (size_t)pl*HW + (size_t)kx*256;
  float2 x0=h2f(col[j]), x1=h2f(col[j+64]), x2=h2f(col[j+128]), x3=h2f(col[j+192]);
  fft256<-1>(tile[g], j, wA,wB,wC, x0,x1,x2,x3);
  tile[g][j]=x0; tile[g][j+64]=x1; tile[g][j+128]=x2; tile[g][j+192]=x3;
  __syncthreads();
  // row-major fp16 scatter: 512 float4 (each = 4 consecutive kx), 1 per thread
  {
    int yc = tid >> 1, ch = tid & 1;
    float4 pkf;
    __half2* pk = (__half2*)&pkf;
    #pragma unroll
    for (int k4 = 0; k4 < 4; k4++) pk[k4] = f2h(tile[ch*4+k4][yc]);
    __half2* d = dst + (size_t)pl*HW + (size_t)yc*256 + kg*8 + ch*4;
    *(float4*)d = pkf;
  }
}

// ---------- b = D*sum_c conj(S_c)*A16 + lambda*mo ; r0 = b ; z=0 ; rs0 partial
__global__ __launch_bounds__(256) void k_compute_b(const __half2* __restrict__ A,
                                                   const float2* __restrict__ sens,
                                                   const float2* __restrict__ mo,
                                                   float2* __restrict__ r,
                                                   float2* __restrict__ z,
                                                   float* __restrict__ part){
  __shared__ float red[4];
  int idx = blockIdx.x*256 + threadIdx.x;
  int s = idx >> 16, pix = idx & (HW-1);
  int xx = pix & 255, yy = pix >> 8;
  float sg = ((xx + yy) & 1) ? -1.0f : 1.0f;
  float2 accv = make_float2(0,0);
  for (int c = 0; c < NC; c++)
    accv = cadd(accv, cmulj(sens[(size_t)c*HW + pix], h2f(A[((size_t)(c*3+s))*HW + pix])));
  float2 b = cadd(cscale(accv, sg), cscale(mo[idx], LAMBDA_F));
  r[idx] = b; z[idx] = make_float2(0,0);
  float partv = b.x*b.x + b.y*b.y;
  for (int off = 32; off; off >>= 1) partv += __shfl_down(partv, off);
  int j = threadIdx.x & 63, w = threadIdx.x >> 6;
  if (j == 0) red[w] = partv;
  __syncthreads();
  if (threadIdx.x == 0) part[ROW_RS(0)*1024 + blockIdx.x] = red[0]+red[1]+red[2]+red[3];
}

// ---------- R-FFT kernel: (S16_c * r)*RF_SCALE -> row FFT(+1) -> bufA16
// transposed [pl][kx][y]. All reads contiguous; 16B-chunk transposed writes.
__global__ __launch_bounds__(512) void k_rfft(const float2* __restrict__ rbuf,
                                              const __half2* __restrict__ sens16,
                                              __half2* __restrict__ dst){
  __shared__ float2 T[8][3][256];   // 48 KB
  int tid = threadIdx.x, g = tid >> 6, j = tid & 63;
  float2 wA = twf((j&3)<<4), wB = twf((j&15)<<2), wC = twf(j);
  int ri = blockIdx.x, c = blockIdx.y;
  int row = ri*8 + g;
  const __half2* Sc = sens16 + (size_t)c*HW + row*256;
  float2 sv[4];
  #pragma unroll
  for (int q = 0; q < 4; q++) sv[q] = cscale(h2f(Sc[j + 64*q]), RF_SCALE);
  #pragma unroll
  for (int s = 0; s < 3; s++){
    const float2* rr = rbuf + (size_t)s*HW + row*256;
    float2 x0 = cmul(sv[0], rr[j]);
    float2 x1 = cmul(sv[1], rr[j+64]);
    float2 x2 = cmul(sv[2], rr[j+128]);
    float2 x3 = cmul(sv[3], rr[j+192]);
    fft256<1>(T[g][s], j, wA,wB,wC, x0,x1,x2,x3);
    T[g][s][j]=x0; T[g][s][j+64]=x1; T[g][s][j+128]=x2; T[g][s][j+192]=x3;
  }
  __syncthreads();
  // transposed scatter as fp16, 16B chunks (4 y-values per write)
  #pragma unroll
  for (int f = 0; f < 3; f++){
    int flat = f*512 + tid;           // 0..1535
    int s = flat >> 9, rem = flat & 511, kx = rem >> 1, ch = rem & 1;
    float4 pkf;                       // 16B-aligned backing store
    __half2* pk = (__half2*)&pkf;
    #pragma unroll
    for (int rr = 0; rr < 4; rr++) pk[rr] = f2h(T[ch*4+rr][s][kx]);
    __half2* dT = dst + ((size_t)(c*3+s))*HW + (size_t)kx*256 + ri*8 + ch*4;
    *(float4*)dT = pkf;
  }
}

// ---------- COL kernel: bufA16 transposed -> CONTIGUOUS column reads -> col
// FFT(+1) -> U = W V (+ rMr Parseval, x256 scale comp) -> col IFFT(-1) ->
// bufB16 row-major 16B-chunk writes (scaled by BW_SCALE for fp16 range).
__global__ __launch_bounds__(384) void k_colW(const __half2* __restrict__ bufA,
                                              __half2* __restrict__ bufB,
                                              const float* __restrict__ W9,
                                              float* __restrict__ part, int iter){
  __shared__ float2 T[12][256];   // 24 KB: [s*4 + local_col][row]
  __shared__ float redp[6];
  int tid = threadIdx.x, w = tid >> 6, j = tid & 63;
  float2 wA = twf((j&3)<<4), wB = twf((j&15)<<2), wC = twf(j);
  int kg = blockIdx.x, c = blockIdx.y;
  int s = w >> 1, kxp = w & 1;
  int kxl0 = kxp*2, kxl1 = kxl0 + 1;
  int kx0 = kg*4 + kxl0, kx1 = kg*4 + kxl1;

  // --- direct contiguous column reads (fp16) + col FFT(+1), 2 cols per wave
  {
    const __half2* colA = bufA + ((size_t)(c*3+s))*HW + (size_t)kx0*256;
    const __half2* colB = bufA + ((size_t)(c*3+s))*HW + (size_t)kx1*256;
    float2 a0=h2f(colA[j]), a1=h2f(colA[j+64]), a2=h2f(colA[j+128]), a3=h2f(colA[j+192]);
    float2 b0=h2f(colB[j]), b1=h2f(colB[j+64]), b2=h2f(colB[j+128]), b3=h2f(colB[j+192]);
    fft256x2<1>(T[s*4+kxl0], T[s*4+kxl1], j, wA,wB,wC, a0,a1,a2,a3, b0,b1,b2,b3);
    T[s*4+kxl0][j]=a0; T[s*4+kxl0][j+64]=a1; T[s*4+kxl0][j+128]=a2; T[s*4+kxl0][j+192]=a3;
    T[s*4+kxl1][j]=b0; T[s*4+kxl1][j+64]=b1; T[s*4+kxl1][j+128]=b2; T[s*4+kxl1][j+192]=b3;
  }
  __syncthreads();

  // --- U = W V + Parseval rMr partial (Re only)
  float2 UA[4], UB[4];
  float pr = 0.f;
  #pragma unroll
  for (int q = 0; q < 4; q++){
    int k = j + 64*q;
    {
      float2 v0 = T[0+kxl0][k], v1 = T[4+kxl0][k], v2 = T[8+kxl0][k];
      float2 U = w_combine(W9, kx0*256 + k, s, v0, v1, v2);
      UA[q] = U;
      float2 vs = (s==0) ? v0 : ((s==1) ? v1 : v2);
      pr += vs.x*U.x + vs.y*U.y;
    }
    {
      float2 v0 = T[0+kxl1][k], v1 = T[4+kxl1][k], v2 = T[8+kxl1][k];
      float2 U = w_combine(W9, kx1*256 + k, s, v0, v1, v2);
      UB[q] = U;
      float2 vs = (s==0) ? v0 : ((s==1) ? v1 : v2);
      pr += vs.x*U.x + vs.y*U.y;
    }
  }
  __syncthreads();   // all V reads done before T reused as IFFT scratch

  // --- col IFFT(-1)
  {
    float2 a0=UA[0], a1=UA[1], a2=UA[2], a3=UA[3];
    float2 b0=UB[0], b1=UB[1], b2=UB[2], b3=UB[3];
    fft256x2<-1>(T[s*4+kxl0], T[s*4+kxl1], j, wA,wB,wC, a0,a1,a2,a3, b0,b1,b2,b3);
    T[s*4+kxl0][j]=a0; T[s*4+kxl0][j+64]=a1; T[s*4+kxl0][j+128]=a2; T[s*4+kxl0][j+192]=a3;
    T[s*4+kxl1][j]=b0; T[s*4+kxl1][j+64]=b1; T[s*4+kxl1][j+128]=b2; T[s*4+kxl1][j+192]=b3;
  }
  // --- reduce rMr partial (x256 compensates RF_SCALE^2 * W9 scale vs r13)
  for (int off = 32; off; off >>= 1) pr += __shfl_down(pr, off);
  if (j == 0) redp[w] = pr;
  __syncthreads();
  if (tid == 0){
    float t = 0.f;
    #pragma unroll
    for (int k = 0; k < 6; k++) t += redp[k];
    part[ROW_RMR(iter)*1024 + c*64 + kg] = t * 256.0f;
  }
  // --- scatter to bufB16 row-major (16B chunks: 4 kx per write), /32 range scale
  #pragma unroll
  for (int f = 0; f < 2; f++){
    int flat = f*384 + tid;           // 0..767
    int s_out = flat >> 8, yc = flat & 255;
    float4 pkf;                       // 16B-aligned backing store
    __half2* pk = (__half2*)&pkf;
    #pragma unroll
    for (int k4 = 0; k4 < 4; k4++) pk[k4] = f2h(cscale(T[s_out*4+k4][yc], BW_SCALE));
    __half2* d = bufB + ((size_t)(c*3+s_out))*HW + (size_t)yc*256 + kg*4;
    *(float4*)d = pkf;
  }
}

// ---------- UPDATE kernel (iter >= 1). grid (256 rows, 3 s), 640 thr = 10 waves.
// bufB16 holds K2(S r_{it-1})*BW_SCALE; row-IFFT(x BW_INV) + conj(S16) combine =
// Mr_{it-1}; scalar chain -> alpha,beta; p/Mp/z/r updates; rs_it partial.
__global__ __launch_bounds__(640) void k_update(const __half2* __restrict__ bufB,
                                                const __half2* __restrict__ sens16,
                                                float2* __restrict__ rbuf,
                                                float2* __restrict__ pbuf,
                                                float2* __restrict__ Mpb,
                                                float2* __restrict__ zbuf,
                                                float* __restrict__ scal,
                                                float* __restrict__ part, int iter){
  __shared__ float2 scratch[10][256];
  __shared__ float redv[10];
  __shared__ float sA[2];
  int tid = threadIdx.x, w = tid >> 6, j = tid & 63;
  float2 wA = twf((j&3)<<4), wB = twf((j&15)<<2), wC = twf(j);
  int row = blockIdx.x, s = blockIdx.y;

  // --- reduce fresh scalar partials: rs_{it-1} (768) and rMr_{it-1} (640)
  int rowsel[2] = { ROW_RS(iter-1), ROW_RMR(iter-1) };
  #pragma unroll
  for (int q = 0; q < 2; q++){
    const float* P = part + rowsel[q]*1024;
    float v = P[tid] + ((tid < 384) ? P[tid+640] : 0.f);
    for (int off = 32; off; off >>= 1) v += __shfl_down(v, off);
    if (j == 0) redv[w] = v;
    __syncthreads();
    if (tid == 0){
      float t = 0.f;
      #pragma unroll
      for (int k = 0; k < 10; k++) t += redv[k];
      sA[q] = t;
    }
    __syncthreads();
  }
  float alpha, beta;
  cg_chain3(scal, iter, sA[0], sA[1], alpha, beta);
  if (blockIdx.x == 0 && blockIdx.y == 0 && tid == 0){
    scal[iter-1]    = sA[0];
    scal[32+iter-1] = sA[1];
  }

  // --- phase 1: row IFFT of bufB16 per coil (undo BW_SCALE) + conj(S16)
  {
    int c = w;
    const __half2* src = bufB + ((size_t)(c*3+s))*HW + row*256;
    float2 x0=cscale(h2f(src[j]),     BW_INV);
    float2 x1=cscale(h2f(src[j+64]),  BW_INV);
    float2 x2=cscale(h2f(src[j+128]), BW_INV);
    float2 x3=cscale(h2f(src[j+192]), BW_INV);
    fft256<-1>(scratch[c], j, wA,wB,wC, x0,x1,x2,x3);
    const __half2* Sc = sens16 + (size_t)c*HW + row*256;
    scratch[c][j]     = cmulj(h2f(Sc[j]),     x0);
    scratch[c][j+64]  = cmulj(h2f(Sc[j+64]),  x1);
    scratch[c][j+128] = cmulj(h2f(Sc[j+128]), x2);
    scratch[c][j+192] = cmulj(h2f(Sc[j+192]), x3);
  }
  __syncthreads();
  // --- phase 2: combine -> Mr; CG updates (threads 0..255)
  if (tid < 256){
    int k = tid;
    float2 Mr = make_float2(0,0);
    #pragma unroll
    for (int c = 0; c < NC; c++) Mr = cadd(Mr, scratch[c][k]);
    size_t ob = (size_t)s*HW + row*256 + k;
    float2 rold = rbuf[ob];
    float2 pcur, Mpc;
    if (iter == 1){ pcur = rold; Mpc = Mr; }
    else {
      pcur = cadd(rold, cscale(pbuf[ob], beta));
      Mpc  = cadd(Mr,   cscale(Mpb[ob],  beta));
    }
    Mpb[ob]  = Mpc;
    pbuf[ob] = pcur;
    float2 Ap = cadd(Mpc, cscale(pcur, LAMBDA_F));
    float2 zo = zbuf[ob];
    zbuf[ob] = make_float2(zo.x + alpha*pcur.x, zo.y + alpha*pcur.y);
    float2 rnew = make_float2(rold.x - alpha*Ap.x, rold.y - alpha*Ap.y);
    rbuf[ob] = rnew;
    float pv2 = rnew.x*rnew.x + rnew.y*rnew.y;
    for (int off = 32; off; off >>= 1) pv2 += __shfl_down(pv2, off);
    if (j == 0) redv[w] = pv2;   // w in 0..3 here
  }
  __syncthreads();
  if (tid == 0)
    part[ROW_RS(iter)*1024 + s*256 + row] = redv[0]+redv[1]+redv[2]+redv[3];
}

// ---------- final: reduce rs_9, rMr_9 ; p9 = r9 + beta9*p8 ; z += alpha9*p9
__global__ __launch_bounds__(256) void k_final(float2* __restrict__ z,
                                               const float2* __restrict__ rbuf,
                                               const float2* __restrict__ pbuf,
                                               const float* __restrict__ scal,
                                               const float* __restrict__ part){
  __shared__ float redv[4];
  __shared__ float sA[2];
  int tid = threadIdx.x, w = tid >> 6, j = tid & 63;
  int rowsel[2] = { ROW_RS(9), ROW_RMR(9) };
  #pragma unroll
  for (int q = 0; q < 2; q++){
    const float* P = part + rowsel[q]*1024;
    float v = P[tid] + P[tid+256] + P[tid+512] + P[tid+768];
    for (int off = 32; off; off >>= 1) v += __shfl_down(v, off);
    if (j == 0) redv[w] = v;
    __syncthreads();
    if (tid == 0) sA[q] = redv[0]+redv[1]+redv[2]+redv[3];
    __syncthreads();
  }
  float alpha, beta;
  cg_chain3(scal, 10, sA[0], sA[1], alpha, beta);
  int idx = blockIdx.x*256 + tid;
  float2 r9 = rbuf[idx], p8 = pbuf[idx];
  float2 p9 = cadd(r9, cscale(p8, beta));
  float2 zo = z[idx];
  z[idx] = make_float2(zo.x + alpha*p9.x, zo.y + alpha*p9.y);
}

extern "C" void kernel_launch(void* const* d_in, const int* in_sizes, int n_in,
                              void* d_out, int out_size, void* d_ws, size_t ws_size,
                              hipStream_t stream){
  const float2* y    = (const float2*)d_in[0];
  const float2* mo   = (const float2*)d_in[1];
  const float2* sens = (const float2*)d_in[2];
  const float2* Lt   = (const float2*)d_in[3];
  const float*  mask = (const float*)d_in[4];

  float* w = (float*)d_ws;
  float*  scal = w;                                   // 128 floats (rs chain + rMr chain)
  float*  part = w + 128;                             // 26*1024 floats
  float*  W9   = part + NPART_ROWS*1024;              // 9*HW floats
  float2* bufA = (float2*)(W9 + 9*HW);                // fp16 staging lives here
  float2* bufB = bufA + (size_t)30*HW;
  float2* rb   = bufB + (size_t)30*HW;                // 3 planes residual
  float2* pb   = rb + (size_t)3*HW;                   // 3 planes direction
  float2* Mpb  = pb + (size_t)3*HW;                   // 3 planes M*p recurrence
  __half2* sens16 = (__half2*)(Mpb + (size_t)3*HW);   // 10 planes fp16 sens
  float2* z    = (float2*)d_out;
  __half2* bufA16 = (__half2*)bufA;                   // 30 planes transposed k-space
  __half2* bufB16 = (__half2*)bufB;                   // 30 planes row-major

  // setup: W9+sens16 ; g+rowIFFT->bufA16_T ; colIFFT->bufB16(A) ; b -> r0,z,rs0
  k_W9<<<416, 256, 0, stream>>>(mask, Lt, sens, W9, sens16, scal, part);
  k_rows_g<<<dim3(32, 10), 512, 0, stream>>>(y, Lt, bufA16);
  k_cols_plain<<<dim3(32, 30), 512, 0, stream>>>(bufA16, bufB16);
  k_compute_b<<<768, 256, 0, stream>>>(bufB16, sens, mo, rb, z, part);

  // CG loop: rfft -> colW -> update (all reads contiguous, fp16 staging)
  for (int it = 0; it < 10; it++){
    k_rfft<<<dim3(32, 10), 512, 0, stream>>>(rb, sens16, bufA16);
    k_colW<<<dim3(64, 10), 384, 0, stream>>>(bufA16, bufB16, W9, part, it);
    if (it < 9)
      k_update<<<dim3(256, 3), 640, 0, stream>>>(bufB16, sens16, rb, pb, Mpb, z, scal, part, it+1);
  }
  k_final<<<768, 256, 0, stream>>>(z, rb, pb, scal, part);
}